// Round 1
// baseline (2287.700 us; speedup 1.0000x reference)
//
#include <hip/hip_runtime.h>
#include <cmath>
#include <complex>
#include <vector>

#define NN 4096
#define BB 4
#define CCH 8

// workspace float offsets
#define OFF_W3JVAL 0         // 2670 floats (padded region to 2688)
#define OFF_W3JOUT 2688      // 10648 floats -> ends 13336
#define OFF_BW     13440     // 48
#define OFF_SCAL   13504     // 64
#define OFF_Q      13568     // B*N*22 = 360448 -> ends 374016
#define OFF_VP     374016    // B*N*192 = 3145728 -> ends 3519744
#define OFF_CTX    3519744   // B*N*192 -> ends 6665472 (~26.7 MB)

// ---------------------------------------------------------------- host: Wigner 3j
namespace {
double dfact(int n){ double r=1.0; for(int i=2;i<=n;++i) r*=(double)i; return r; }

void compute_w3j(int l1,int l2,int l3,double scale,float* dst){
  int d1=2*l1+1,d2=2*l2+1,d3=2*l3+1;
  std::vector<double> Cc((size_t)d1*d2*d3,0.0);
  for(int i=0;i<d1;i++){int m1=i-l1;
   for(int j=0;j<d2;j++){int m2=j-l2;
    for(int k=0;k<d3;k++){int m3=k-l3;
      if(m1+m2!=m3) continue;
      double pref = std::sqrt((2.0*l3+1.0)*dfact(l3+l1-l2)*dfact(l3-l1+l2)*dfact(l1+l2-l3)/dfact(l1+l2+l3+1));
      pref *= std::sqrt(dfact(l3+m3)*dfact(l3-m3)*dfact(l1-m1)*dfact(l1+m1)*dfact(l2-m2)*dfact(l2+m2));
      double s=0.0;
      for(int kk=0;kk<=l1+l2-l3;kk++){
        int dd[6]={kk,l1+l2-l3-kk,l1-m1-kk,l2+m2-kk,l3-l2+m1+kk,l3-l1-m2+kk};
        int mn=dd[0]; for(int t=1;t<6;t++) if(dd[t]<mn) mn=dd[t];
        if(mn<0) continue;
        double prod=1.0; for(int t=0;t<6;t++) prod*=dfact(dd[t]);
        s += ((kk&1)?-1.0:1.0)/prod;
      }
      Cc[((size_t)i*d2+j)*d3+k]=pref*s;
    }}}
  auto qmat=[](int l){
    int d=2*l+1;
    std::vector<std::complex<double>> q((size_t)d*d,std::complex<double>(0,0));
    double rs2=1.0/std::sqrt(2.0);
    for(int m=-l;m<0;m++){
      q[(size_t)(l+m)*d+(l-m)]=std::complex<double>(rs2,0);
      q[(size_t)(l+m)*d+(l+m)]=std::complex<double>(0,-rs2);
    }
    q[(size_t)l*d+l]=std::complex<double>(1,0);
    for(int m=1;m<=l;m++){
      double sg=(m&1)?-1.0:1.0;
      q[(size_t)(l+m)*d+(l+m)]=std::complex<double>(sg*rs2,0);
      q[(size_t)(l+m)*d+(l-m)]=std::complex<double>(0,sg*rs2);
    }
    std::complex<double> f(1,0),mi(0,-1);
    for(int t=0;t<l;t++) f*=mi;
    for(auto&z:q) z*=f;
    return q;
  };
  auto Q1=qmat(l1),Q2=qmat(l2),Q3=qmat(l3);
  std::vector<std::complex<double>> T1((size_t)d1*d2*d3), T2((size_t)d1*d2*d3);
  for(int j=0;j<d1;j++) for(int k=0;k<d2;k++) for(int m=0;m<d3;m++){
    std::complex<double> s(0,0);
    for(int i=0;i<d1;i++) s += Q1[(size_t)i*d1+j]*Cc[((size_t)i*d2+k)*d3+m];
    T1[((size_t)j*d2+k)*d3+m]=s;
  }
  for(int j=0;j<d1;j++) for(int l=0;l<d2;l++) for(int m=0;m<d3;m++){
    std::complex<double> s(0,0);
    for(int k=0;k<d2;k++) s += Q2[(size_t)k*d2+l]*T1[((size_t)j*d2+k)*d3+m];
    T2[((size_t)j*d2+l)*d3+m]=s;
  }
  std::vector<double> Cr((size_t)d1*d2*d3);
  double nrm=0.0;
  for(int j=0;j<d1;j++) for(int l=0;l<d2;l++) for(int n=0;n<d3;n++){
    std::complex<double> s(0,0);
    for(int m=0;m<d3;m++) s += std::conj(Q3[(size_t)m*d3+n])*T2[((size_t)j*d2+l)*d3+m];
    double v=s.real();
    Cr[((size_t)j*d2+l)*d3+n]=v; nrm+=v*v;
  }
  nrm=std::sqrt(nrm);
  double c=scale/nrm;
  for(size_t t=0;t<Cr.size();t++) dst[t]=(float)(Cr[t]*c);
}
} // namespace

// ---------------------------------------------------------------- k_weights
// bw[p][w]   = sum_u wli[l1(p)][u]*w_val[p][u][w]                (6 val paths)
// scal[p][v] = (1/sqrt(C)) sum_{u,w} w_out[p][u][v][w]*wli[l1(p)][u]*wlo[l3(p)][w]
__global__ void k_weights(const float* __restrict__ wli, const float* __restrict__ wval,
                          const float* __restrict__ wout, const float* __restrict__ wlo,
                          float* __restrict__ bw, float* __restrict__ scal){
  int t = threadIdx.x;
  const int val_l1[6]={0,0,1,0,1,1};
  const int out_l1[8]={0,0,1,1,0,0,1,1};
  const int out_l3[8]={0,0,0,0,1,1,1,1};
  if(t<48){
    int p=t>>3, w=t&7;
    float s=0.f;
    for(int u=0;u<8;u++) s = fmaf(wli[val_l1[p]*8+u], wval[(p*8+u)*8+w], s);
    bw[t]=s;
  }
  {
    int p=t>>3, v=t&7;
    float s=0.f;
    for(int u=0;u<8;u++){
      float a=wli[out_l1[p]*8+u];
      for(int w=0;w<8;w++) s = fmaf(wout[((p*8+u)*8+v)*8+w]*a, wlo[out_l3[p]*8+w], s);
    }
    scal[t]=s*0.35355339059327373f; // 1/sqrt(8)
  }
}

// ---------------------------------------------------------------- k_prep
// per point: Q row (scaled normalized 22-dim), Vp row (176 vals * e^pb, col176=e^pb, pad zeros)
__global__ void k_prep(const float* __restrict__ feat, const float* __restrict__ sh,
                       const float* __restrict__ log_s, const float* __restrict__ pos_w,
                       const float* __restrict__ pos_b, const float* __restrict__ w3jval,
                       const float* __restrict__ bw, float* __restrict__ Q,
                       float* __restrict__ Vp){
  __shared__ float Wv[2670];
  __shared__ float bws[48];
  for(int i=threadIdx.x;i<2670;i+=256) Wv[i]=w3jval[i];
  if(threadIdx.x<48) bws[threadIdx.x]=bw[threadIdx.x];
  __syncthreads();
  int idx = blockIdx.x*256 + threadIdx.x;   // 0..16383
  int n = idx & (NN-1);
  const float* fp = feat + (size_t)idx*22;
  const float* shp = sh + n*6;
  float f[22];
  #pragma unroll
  for(int c=0;c<22;c++) f[c]=fp[c];
  float n4=0.f, n6=0.f;
  #pragma unroll
  for(int c=0;c<9;c++) n4 += f[c]*f[c];
  #pragma unroll
  for(int c=9;c<22;c++) n6 += f[c]*f[c];
  n4 = fmaxf(sqrtf(n4), 1e-12f);
  n6 = fmaxf(sqrtf(n6), 1e-12f);
  float s4 = __expf(log_s[0]), s6 = __expf(log_s[1]);
  float a4 = sqrtf(s4)/n4, a6 = sqrtf(s6)/n6;
  float* qp = Q + (size_t)idx*22;
  #pragma unroll
  for(int c=0;c<9;c++) qp[c]=f[c]*a4;
  #pragma unroll
  for(int c=9;c<22;c++) qp[c]=f[c]*a6;
  float pb = pos_b[0];
  #pragma unroll
  for(int j=0;j<6;j++) pb = fmaf(shp[j], pos_w[j], pb);
  float epb = __expf(pb);
  float y0 = shp[0];
  float y2[5];
  #pragma unroll
  for(int j=0;j<5;j++) y2[j]=shp[1+j];

  float t0[9],t1[9],t2[9],t3[13],t4[13],t5[13];
  #pragma unroll
  for(int k=0;k<9;k++){t0[k]=0.f;t1[k]=0.f;t2[k]=0.f;}
  #pragma unroll
  for(int k=0;k<13;k++){t3[k]=0.f;t4[k]=0.f;t5[k]=0.f;}
  // p0 (4,0,4) dims (9,1,9) off 0
  for(int i=0;i<9;i++){ float fi=fp[i];
    #pragma unroll
    for(int k=0;k<9;k++) t0[k]=fmaf(fi,Wv[i*9+k],t0[k]); }
  #pragma unroll
  for(int k=0;k<9;k++) t0[k]*=y0;
  // p1 (4,2,4) dims (9,5,9) off 81
  for(int i=0;i<9;i++){ float fi=fp[i];
    #pragma unroll
    for(int j=0;j<5;j++){ float c_=fi*y2[j];
      #pragma unroll
      for(int k=0;k<9;k++) t1[k]=fmaf(c_,Wv[81+(i*5+j)*9+k],t1[k]); } }
  // p2 (6,2,4) dims (13,5,9) off 486
  for(int i=0;i<13;i++){ float fi=fp[9+i];
    #pragma unroll
    for(int j=0;j<5;j++){ float c_=fi*y2[j];
      #pragma unroll
      for(int k=0;k<9;k++) t2[k]=fmaf(c_,Wv[486+(i*5+j)*9+k],t2[k]); } }
  // p3 (4,2,6) dims (9,5,13) off 1071
  for(int i=0;i<9;i++){ float fi=fp[i];
    #pragma unroll
    for(int j=0;j<5;j++){ float c_=fi*y2[j];
      #pragma unroll
      for(int k=0;k<13;k++) t3[k]=fmaf(c_,Wv[1071+(i*5+j)*13+k],t3[k]); } }
  // p4 (6,0,6) dims (13,1,13) off 1656
  for(int i=0;i<13;i++){ float fi=fp[9+i];
    #pragma unroll
    for(int k=0;k<13;k++) t4[k]=fmaf(fi,Wv[1656+i*13+k],t4[k]); }
  #pragma unroll
  for(int k=0;k<13;k++) t4[k]*=y0;
  // p5 (6,2,6) dims (13,5,13) off 1825
  for(int i=0;i<13;i++){ float fi=fp[9+i];
    #pragma unroll
    for(int j=0;j<5;j++){ float c_=fi*y2[j];
      #pragma unroll
      for(int k=0;k<13;k++) t5[k]=fmaf(c_,Wv[1825+(i*5+j)*13+k],t5[k]); } }

  float* vout = Vp + (size_t)idx*192;
  for(int w=0;w<8;w++){
    float b0=bws[w], b1=bws[8+w], b2=bws[16+w];
    #pragma unroll
    for(int k=0;k<9;k++) vout[w*9+k] = epb*(b0*t0[k]+b1*t1[k]+b2*t2[k]);
  }
  for(int w=0;w<8;w++){
    float b3=bws[24+w], b4=bws[32+w], b5=bws[40+w];
    #pragma unroll
    for(int k=0;k<13;k++) vout[72+w*13+k] = epb*(b3*t3[k]+b4*t4[k]+b5*t5[k]);
  }
  vout[176]=epb;
  #pragma unroll
  for(int c=177;c<192;c++) vout[c]=0.f;
}

// ---------------------------------------------------------------- k_attn
// ctx_num[b,n,0:177] = sum_m exp(q_n . q_m) * Vp[b,m,:]   (col 176 = denominator)
#define RT 32     // rows per workgroup
#define CTile 64  // m per tile
__launch_bounds__(256, 2)
__global__ void k_attn(const float* __restrict__ Q, const float* __restrict__ Vp,
                       float* __restrict__ ctx){
  __shared__ float Ks[CTile][26];    // 6656 B
  __shared__ float Vs[CTile][192];   // 49152 B
  __shared__ float Es[CTile][34];    // 8704 B  -> total 64512 B
  int tid = threadIdx.x;
  int b  = blockIdx.x & 3;           // aligns batch with XCD round-robin for L2 locality
  int rt = blockIdx.x >> 2;
  int row0 = rt * RT;
  const float* Qb = Q  + (size_t)b*NN*22;
  const float* Vb = Vp + (size_t)b*NN*192;

  int er = tid & 15;                 // E-phase row group (2 rows)
  int em = tid >> 4;                 // E-phase m group (4 cols)
  int m0 = em*4;
  float qreg[2][22];
  {
    const float* qp = Qb + (size_t)(row0 + er*2)*22;
    #pragma unroll
    for(int c=0;c<22;c++){ qreg[0][c]=qp[c]; qreg[1][c]=qp[22+c]; }
  }
  int x = tid & 15;                  // PV feature group (12 cols)
  int y = tid >> 4;                  // PV row group (2 rows)
  int f0 = x*12;
  int r0 = y*2;
  float a0[12], a1[12];
  #pragma unroll
  for(int c=0;c<12;c++){ a0[c]=0.f; a1[c]=0.f; }

  for(int mt=0; mt<NN/CTile; ++mt){
    int mg = mt*CTile;
    // stage K rows (contiguous 1408 floats)
    for(int i=tid;i<CTile*22;i+=256){
      int r=i/22, c=i-r*22;
      Ks[r][c] = Qb[(size_t)mg*22 + i];
    }
    // stage V rows (flat float4 copy, rows contiguous in both layouts)
    {
      const float4* src = (const float4*)(Vb + (size_t)mg*192);
      float4* dst = (float4*)(&Vs[0][0]);
      for(int i=tid;i<CTile*48;i+=256) dst[i]=src[i];
    }
    __syncthreads();
    // E phase: scores + exp, store transposed Es[m][r]
    float sa[2][4]={{0,0,0,0},{0,0,0,0}};
    #pragma unroll
    for(int kk=0;kk<11;kk++){
      float q00=qreg[0][2*kk], q01=qreg[0][2*kk+1];
      float q10=qreg[1][2*kk], q11=qreg[1][2*kk+1];
      #pragma unroll
      for(int j=0;j<4;j++){
        float2 kv = *(const float2*)&Ks[m0+j][2*kk];
        sa[0][j] = fmaf(q00,kv.x,fmaf(q01,kv.y,sa[0][j]));
        sa[1][j] = fmaf(q10,kv.x,fmaf(q11,kv.y,sa[1][j]));
      }
    }
    #pragma unroll
    for(int j=0;j<4;j++){
      float2 ev; ev.x=__expf(sa[0][j]); ev.y=__expf(sa[1][j]);
      *(float2*)&Es[m0+j][er*2] = ev;
    }
    __syncthreads();
    // PV phase: rank-1 accumulate 2 rows x 12 feats per thread
    #pragma unroll 4
    for(int m=0;m<CTile;m++){
      float2 e = *(const float2*)&Es[m][r0];
      const float* vp = &Vs[m][f0];
      float4 v0=*(const float4*)(vp);
      float4 v1=*(const float4*)(vp+4);
      float4 v2=*(const float4*)(vp+8);
      a0[0]=fmaf(e.x,v0.x,a0[0]); a0[1]=fmaf(e.x,v0.y,a0[1]); a0[2]=fmaf(e.x,v0.z,a0[2]); a0[3]=fmaf(e.x,v0.w,a0[3]);
      a0[4]=fmaf(e.x,v1.x,a0[4]); a0[5]=fmaf(e.x,v1.y,a0[5]); a0[6]=fmaf(e.x,v1.z,a0[6]); a0[7]=fmaf(e.x,v1.w,a0[7]);
      a0[8]=fmaf(e.x,v2.x,a0[8]); a0[9]=fmaf(e.x,v2.y,a0[9]); a0[10]=fmaf(e.x,v2.z,a0[10]); a0[11]=fmaf(e.x,v2.w,a0[11]);
      a1[0]=fmaf(e.y,v0.x,a1[0]); a1[1]=fmaf(e.y,v0.y,a1[1]); a1[2]=fmaf(e.y,v0.z,a1[2]); a1[3]=fmaf(e.y,v0.w,a1[3]);
      a1[4]=fmaf(e.y,v1.x,a1[4]); a1[5]=fmaf(e.y,v1.y,a1[5]); a1[6]=fmaf(e.y,v1.z,a1[6]); a1[7]=fmaf(e.y,v1.w,a1[7]);
      a1[8]=fmaf(e.y,v2.x,a1[8]); a1[9]=fmaf(e.y,v2.y,a1[9]); a1[10]=fmaf(e.y,v2.z,a1[10]); a1[11]=fmaf(e.y,v2.w,a1[11]);
    }
    __syncthreads();
  }
  float* cp0 = ctx + ((size_t)(b*NN + row0 + r0))*192 + f0;
  ((float4*)cp0)[0]=make_float4(a0[0],a0[1],a0[2],a0[3]);
  ((float4*)cp0)[1]=make_float4(a0[4],a0[5],a0[6],a0[7]);
  ((float4*)cp0)[2]=make_float4(a0[8],a0[9],a0[10],a0[11]);
  float* cp1 = cp0 + 192;
  ((float4*)cp1)[0]=make_float4(a1[0],a1[1],a1[2],a1[3]);
  ((float4*)cp1)[1]=make_float4(a1[4],a1[5],a1[6],a1[7]);
  ((float4*)cp1)[2]=make_float4(a1[8],a1[9],a1[10],a1[11]);
}

// ---------------------------------------------------------------- k_out
__global__ void k_out(const float* __restrict__ feat, const float* __restrict__ ctx,
                      const float* __restrict__ w3jout, const float* __restrict__ scal,
                      float* __restrict__ out){
  __shared__ float Wo[10648];
  __shared__ float sc[64];
  __shared__ float gl[256*13];
  for(int i=threadIdx.x;i<10648;i+=256) Wo[i]=w3jout[i];
  if(threadIdx.x<64) sc[threadIdx.x]=scal[threadIdx.x];
  __syncthreads();
  int tid=threadIdx.x;
  int idx = blockIdx.x*256 + tid;
  const float* fp = feat + (size_t)idx*22;
  const float* cp = ctx + (size_t)idx*192;
  float* g = &gl[tid*13];
  float invden = 1.0f / cp[176];
  float f[22];
  #pragma unroll
  for(int c=0;c<22;c++) f[c]=fp[c];
  float d4[9], d6[13];
  #pragma unroll
  for(int k=0;k<9;k++) d4[k]=0.f;
  #pragma unroll
  for(int k=0;k<13;k++) d6[k]=0.f;

#define PATH(P, ID, JD, KD, FB, CB, OFFS, DST) { \
    for(int j=0;j<(JD);j++){ float s_=0.f; \
      _Pragma("unroll") \
      for(int v=0;v<8;v++) s_ = fmaf(sc[(P)*8+v], cp[(CB)+v*(JD)+j], s_); \
      g[j]=s_; } \
    _Pragma("unroll") \
    for(int i=0;i<(ID);i++){ float fi=f[(FB)+i]; \
      for(int j=0;j<(JD);j++){ float c_=fi*g[j]; \
        _Pragma("unroll") \
        for(int k=0;k<(KD);k++) DST[k] = fmaf(c_, Wo[(OFFS)+(i*(JD)+j)*(KD)+k], DST[k]); } } }

  PATH(0, 9, 9, 9, 0, 0,    0, d4)   // (4,4,4)
  PATH(1, 9,13, 9, 0,72,  729, d4)   // (4,6,4)
  PATH(2,13, 9, 9, 9, 0, 1782, d4)   // (6,4,4)
  PATH(3,13,13, 9, 9,72, 2835, d4)   // (6,6,4)
  PATH(4, 9, 9,13, 0, 0, 4356, d6)   // (4,4,6)
  PATH(5, 9,13,13, 0,72, 5409, d6)   // (4,6,6)
  PATH(6,13, 9,13, 9, 0, 6930, d6)   // (6,4,6)
  PATH(7,13,13,13, 9,72, 8451, d6)   // (6,6,6)
#undef PATH

  float* op = out + (size_t)idx*22;
  #pragma unroll
  for(int k=0;k<9;k++) op[k]=d4[k]*invden;
  #pragma unroll
  for(int k=0;k<13;k++) op[9+k]=d6[k]*invden;
}

// ---------------------------------------------------------------- launch
extern "C" void kernel_launch(void* const* d_in, const int* in_sizes, int n_in,
                              void* d_out, int out_size, void* d_ws, size_t ws_size,
                              hipStream_t stream){
  (void)in_sizes; (void)n_in; (void)out_size; (void)ws_size;
  static float h_tab[13336];
  {
    const int vpth[6][3]={{4,0,4},{4,2,4},{6,2,4},{4,2,6},{6,0,6},{6,2,6}};
    const int voff[6]={0,81,486,1071,1656,1825};
    for(int p=0;p<6;p++){
      double scl = std::sqrt((2.0*vpth[p][2]+1.0)/(3.0*CCH));
      compute_w3j(vpth[p][0],vpth[p][1],vpth[p][2],scl,h_tab+voff[p]);
    }
    const int opth[8][3]={{4,4,4},{4,6,4},{6,4,4},{6,6,4},{4,4,6},{4,6,6},{6,4,6},{6,6,6}};
    const int ooff[8]={0,729,1782,2835,4356,5409,6930,8451};
    for(int p=0;p<8;p++){
      double scl = std::sqrt((2.0*opth[p][2]+1.0)/(4.0*CCH*CCH));
      compute_w3j(opth[p][0],opth[p][1],opth[p][2],scl,h_tab+2688+ooff[p]);
    }
  }
  float* wsf=(float*)d_ws;
  hipMemcpyAsync(wsf, h_tab, sizeof(h_tab), hipMemcpyHostToDevice, stream);

  const float* feat =(const float*)d_in[0];
  const float* sh   =(const float*)d_in[1];
  const float* log_s=(const float*)d_in[2];
  const float* pos_w=(const float*)d_in[3];
  const float* pos_b=(const float*)d_in[4];
  const float* wli  =(const float*)d_in[5];
  const float* wval =(const float*)d_in[6];
  const float* wout =(const float*)d_in[7];
  const float* wlo  =(const float*)d_in[8];
  float* outp=(float*)d_out;

  hipLaunchKernelGGL(k_weights, dim3(1), dim3(64), 0, stream,
                     wli, wval, wout, wlo, wsf+OFF_BW, wsf+OFF_SCAL);
  hipLaunchKernelGGL(k_prep, dim3(64), dim3(256), 0, stream,
                     feat, sh, log_s, pos_w, pos_b, wsf+OFF_W3JVAL, wsf+OFF_BW,
                     wsf+OFF_Q, wsf+OFF_VP);
  hipLaunchKernelGGL(k_attn, dim3(512), dim3(256), 0, stream,
                     wsf+OFF_Q, wsf+OFF_VP, wsf+OFF_CTX);
  hipLaunchKernelGGL(k_out, dim3(64), dim3(256), 0, stream,
                     feat, wsf+OFF_CTX, wsf+OFF_W3JOUT, wsf+OFF_SCAL, outp);
}

// Round 2
// 607.241 us; speedup vs baseline: 3.7674x; 3.7674x over previous
//
#include <hip/hip_runtime.h>
#include <cmath>
#include <complex>
#include <vector>

#define NN 4096
#define BB 4
#define CCH 8
#define KT 64

// ---- workspace float offsets (fp32 region)
#define OFF_W3JVAL 0         // 2670 floats (pad to 2688)
#define OFF_W3JOUT 2688      // 10648 -> ends 13336 (pad 13440)
#define OFF_BW     13440     // 48
#define OFF_SCAL   13504     // 64
#define OFF_VP     13568     // B*N*192 = 3145728 -> ends 3159296
#define OFF_CTX    3159296   // B*N*192 -> ends 6305024 floats
// ---- byte offsets (bf16 region), all 16B aligned
#define OFFB_KGH   25220096ULL   // u16[4*4096*40]  = 1310720 B
#define OFFB_KGL   26530816ULL
#define OFFB_VGH   27841536ULL   // u16[4*64*192*64] = 6291456 B
#define OFFB_VGL   34132992ULL   // end 40424448

typedef short s16x8 __attribute__((ext_vector_type(8)));
typedef float f32x4 __attribute__((ext_vector_type(4)));

static __device__ __forceinline__ unsigned short f2bf(float x){
  unsigned u = __float_as_uint(x);
  return (unsigned short)((u + 0x7FFFu + ((u >> 16) & 1u)) >> 16);
}
static __device__ __forceinline__ float bf2f(unsigned short h){
  return __uint_as_float(((unsigned)h) << 16);
}

// ---------------------------------------------------------------- host: Wigner 3j
namespace {
double dfact(int n){ double r=1.0; for(int i=2;i<=n;++i) r*=(double)i; return r; }

void compute_w3j(int l1,int l2,int l3,double scale,float* dst){
  int d1=2*l1+1,d2=2*l2+1,d3=2*l3+1;
  std::vector<double> Cc((size_t)d1*d2*d3,0.0);
  for(int i=0;i<d1;i++){int m1=i-l1;
   for(int j=0;j<d2;j++){int m2=j-l2;
    for(int k=0;k<d3;k++){int m3=k-l3;
      if(m1+m2!=m3) continue;
      double pref = std::sqrt((2.0*l3+1.0)*dfact(l3+l1-l2)*dfact(l3-l1+l2)*dfact(l1+l2-l3)/dfact(l1+l2+l3+1));
      pref *= std::sqrt(dfact(l3+m3)*dfact(l3-m3)*dfact(l1-m1)*dfact(l1+m1)*dfact(l2-m2)*dfact(l2+m2));
      double s=0.0;
      for(int kk=0;kk<=l1+l2-l3;kk++){
        int dd[6]={kk,l1+l2-l3-kk,l1-m1-kk,l2+m2-kk,l3-l2+m1+kk,l3-l1-m2+kk};
        int mn=dd[0]; for(int t=1;t<6;t++) if(dd[t]<mn) mn=dd[t];
        if(mn<0) continue;
        double prod=1.0; for(int t=0;t<6;t++) prod*=dfact(dd[t]);
        s += ((kk&1)?-1.0:1.0)/prod;
      }
      Cc[((size_t)i*d2+j)*d3+k]=pref*s;
    }}}
  auto qmat=[](int l){
    int d=2*l+1;
    std::vector<std::complex<double>> q((size_t)d*d,std::complex<double>(0,0));
    double rs2=1.0/std::sqrt(2.0);
    for(int m=-l;m<0;m++){
      q[(size_t)(l+m)*d+(l-m)]=std::complex<double>(rs2,0);
      q[(size_t)(l+m)*d+(l+m)]=std::complex<double>(0,-rs2);
    }
    q[(size_t)l*d+l]=std::complex<double>(1,0);
    for(int m=1;m<=l;m++){
      double sg=(m&1)?-1.0:1.0;
      q[(size_t)(l+m)*d+(l+m)]=std::complex<double>(sg*rs2,0);
      q[(size_t)(l+m)*d+(l-m)]=std::complex<double>(0,sg*rs2);
    }
    std::complex<double> f(1,0),mi(0,-1);
    for(int t=0;t<l;t++) f*=mi;
    for(auto&z:q) z*=f;
    return q;
  };
  auto Q1=qmat(l1),Q2=qmat(l2),Q3=qmat(l3);
  std::vector<std::complex<double>> T1((size_t)d1*d2*d3), T2((size_t)d1*d2*d3);
  for(int j=0;j<d1;j++) for(int k=0;k<d2;k++) for(int m=0;m<d3;m++){
    std::complex<double> s(0,0);
    for(int i=0;i<d1;i++) s += Q1[(size_t)i*d1+j]*Cc[((size_t)i*d2+k)*d3+m];
    T1[((size_t)j*d2+k)*d3+m]=s;
  }
  for(int j=0;j<d1;j++) for(int l=0;l<d2;l++) for(int m=0;m<d3;m++){
    std::complex<double> s(0,0);
    for(int k=0;k<d2;k++) s += Q2[(size_t)k*d2+l]*T1[((size_t)j*d2+k)*d3+m];
    T2[((size_t)j*d2+l)*d3+m]=s;
  }
  std::vector<double> Cr((size_t)d1*d2*d3);
  double nrm=0.0;
  for(int j=0;j<d1;j++) for(int l=0;l<d2;l++) for(int n=0;n<d3;n++){
    std::complex<double> s(0,0);
    for(int m=0;m<d3;m++) s += std::conj(Q3[(size_t)m*d3+n])*T2[((size_t)j*d2+l)*d3+m];
    double v=s.real();
    Cr[((size_t)j*d2+l)*d3+n]=v; nrm+=v*v;
  }
  nrm=std::sqrt(nrm);
  double c=scale/nrm;
  for(size_t t=0;t<Cr.size();t++) dst[t]=(float)(Cr[t]*c);
}
} // namespace

// ---------------------------------------------------------------- k_weights
__global__ void k_weights(const float* __restrict__ wli, const float* __restrict__ wval,
                          const float* __restrict__ wout, const float* __restrict__ wlo,
                          float* __restrict__ bw, float* __restrict__ scal){
  int t = threadIdx.x;
  const int val_l1[6]={0,0,1,0,1,1};
  const int out_l1[8]={0,0,1,1,0,0,1,1};
  const int out_l3[8]={0,0,0,0,1,1,1,1};
  if(t<48){
    int p=t>>3, w=t&7;
    float s=0.f;
    for(int u=0;u<8;u++) s = fmaf(wli[val_l1[p]*8+u], wval[(p*8+u)*8+w], s);
    bw[t]=s;
  }
  {
    int p=t>>3, v=t&7;
    float s=0.f;
    for(int u=0;u<8;u++){
      float a=wli[out_l1[p]*8+u];
      for(int w=0;w<8;w++) s = fmaf(wout[((p*8+u)*8+v)*8+w]*a, wlo[out_l3[p]*8+w], s);
    }
    scal[t]=s*0.35355339059327373f; // 1/sqrt(8)
  }
}

// ---------------------------------------------------------------- k_prep
// per point: split-bf16 scaled-normalized q row -> Kgh/Kgl [idx][40] (cols>=22 zero),
// Vp fp32 row [idx][192]: 176 vals * e^pb, col176=e^pb, 177..191 zero
__global__ void k_prep(const float* __restrict__ feat, const float* __restrict__ sh,
                       const float* __restrict__ log_s, const float* __restrict__ pos_w,
                       const float* __restrict__ pos_b, const float* __restrict__ w3jval,
                       const float* __restrict__ bw,
                       unsigned short* __restrict__ Kgh, unsigned short* __restrict__ Kgl,
                       float* __restrict__ Vp){
  __shared__ float Wv[2670];
  __shared__ float bws[48];
  for(int i=threadIdx.x;i<2670;i+=256) Wv[i]=w3jval[i];
  if(threadIdx.x<48) bws[threadIdx.x]=bw[threadIdx.x];
  __syncthreads();
  int idx = blockIdx.x*256 + threadIdx.x;   // 0..16383
  int n = idx & (NN-1);
  const float* fp = feat + (size_t)idx*22;
  const float* shp = sh + n*6;
  float f[22];
  #pragma unroll
  for(int c=0;c<22;c++) f[c]=fp[c];
  float n4=0.f, n6=0.f;
  #pragma unroll
  for(int c=0;c<9;c++) n4 += f[c]*f[c];
  #pragma unroll
  for(int c=9;c<22;c++) n6 += f[c]*f[c];
  n4 = fmaxf(sqrtf(n4), 1e-12f);
  n6 = fmaxf(sqrtf(n6), 1e-12f);
  float s4 = __expf(log_s[0]), s6 = __expf(log_s[1]);
  float a4 = sqrtf(s4)/n4, a6 = sqrtf(s6)/n6;
  {
    unsigned short* kh = Kgh + (size_t)idx*40;
    unsigned short* kl = Kgl + (size_t)idx*40;
    #pragma unroll
    for(int c=0;c<22;c++){
      float qv = f[c] * (c<9 ? a4 : a6);
      unsigned short h = f2bf(qv);
      kh[c]=h; kl[c]=f2bf(qv - bf2f(h));
    }
    #pragma unroll
    for(int c=22;c<40;c++){ kh[c]=0; kl[c]=0; }
  }
  float pb = pos_b[0];
  #pragma unroll
  for(int j=0;j<6;j++) pb = fmaf(shp[j], pos_w[j], pb);
  float epb = __expf(pb);
  float y0 = shp[0];
  float y2[5];
  #pragma unroll
  for(int j=0;j<5;j++) y2[j]=shp[1+j];

  float t0[9],t1[9],t2[9],t3[13],t4[13],t5[13];
  #pragma unroll
  for(int k=0;k<9;k++){t0[k]=0.f;t1[k]=0.f;t2[k]=0.f;}
  #pragma unroll
  for(int k=0;k<13;k++){t3[k]=0.f;t4[k]=0.f;t5[k]=0.f;}
  for(int i=0;i<9;i++){ float fi=fp[i];
    #pragma unroll
    for(int k=0;k<9;k++) t0[k]=fmaf(fi,Wv[i*9+k],t0[k]); }
  #pragma unroll
  for(int k=0;k<9;k++) t0[k]*=y0;
  for(int i=0;i<9;i++){ float fi=fp[i];
    #pragma unroll
    for(int j=0;j<5;j++){ float c_=fi*y2[j];
      #pragma unroll
      for(int k=0;k<9;k++) t1[k]=fmaf(c_,Wv[81+(i*5+j)*9+k],t1[k]); } }
  for(int i=0;i<13;i++){ float fi=fp[9+i];
    #pragma unroll
    for(int j=0;j<5;j++){ float c_=fi*y2[j];
      #pragma unroll
      for(int k=0;k<9;k++) t2[k]=fmaf(c_,Wv[486+(i*5+j)*9+k],t2[k]); } }
  for(int i=0;i<9;i++){ float fi=fp[i];
    #pragma unroll
    for(int j=0;j<5;j++){ float c_=fi*y2[j];
      #pragma unroll
      for(int k=0;k<13;k++) t3[k]=fmaf(c_,Wv[1071+(i*5+j)*13+k],t3[k]); } }
  for(int i=0;i<13;i++){ float fi=fp[9+i];
    #pragma unroll
    for(int k=0;k<13;k++) t4[k]=fmaf(fi,Wv[1656+i*13+k],t4[k]); }
  #pragma unroll
  for(int k=0;k<13;k++) t4[k]*=y0;
  for(int i=0;i<13;i++){ float fi=fp[9+i];
    #pragma unroll
    for(int j=0;j<5;j++){ float c_=fi*y2[j];
      #pragma unroll
      for(int k=0;k<13;k++) t5[k]=fmaf(c_,Wv[1825+(i*5+j)*13+k],t5[k]); } }

  float* vout = Vp + (size_t)idx*192;
  for(int w=0;w<8;w++){
    float b0=bws[w], b1=bws[8+w], b2=bws[16+w];
    #pragma unroll
    for(int k=0;k<9;k++) vout[w*9+k] = epb*(b0*t0[k]+b1*t1[k]+b2*t2[k]);
  }
  for(int w=0;w<8;w++){
    float b3=bws[24+w], b4=bws[32+w], b5=bws[40+w];
    #pragma unroll
    for(int k=0;k<13;k++) vout[72+w*13+k] = epb*(b3*t3[k]+b4*t4[k]+b5*t5[k]);
  }
  vout[176]=epb;
  #pragma unroll
  for(int c=177;c<192;c++) vout[c]=0.f;
}

// ---------------------------------------------------------------- k_split
// transpose+split V: Vp fp32 [b][n][192] -> Vgh/Vgl bf16 [b][panel(64 keys)][192][64]
__global__ void k_split(const float* __restrict__ Vp,
                        unsigned short* __restrict__ Vgh, unsigned short* __restrict__ Vgl){
  __shared__ float Vb[64][193];
  int tid = threadIdx.x;
  int b = blockIdx.x & 3, panel = blockIdx.x >> 2;   // 64 panels per b
  const float* src = Vp + ((size_t)b*NN + (size_t)panel*64)*192;
  for(int i=tid; i<64*192; i+=256){
    int key = i/192, f = i - key*192;
    Vb[key][f] = src[i];
  }
  __syncthreads();
  size_t obase = ((size_t)b*64 + panel)*192*64;
  for(int o=tid; o<192*64; o+=256){
    int f = o>>6, key = o&63;
    float v = Vb[key][f];
    unsigned short h = f2bf(v);
    Vgh[obase+o] = h;
    Vgl[obase+o] = f2bf(v - bf2f(h));
  }
}

// ---------------------------------------------------------------- k_attn (MFMA split-bf16)
// Block: 512 thr (8 waves), 64 q-rows, KT=64 keys/iter. Grid 256 = 4b x 64 qb.
// ctx[b][q][0:192] = sum_m exp(q.k) * V'[m][:]  (col176 = denominator)
__launch_bounds__(512, 2)
__global__ void k_attn(const unsigned short* __restrict__ Kgh,
                       const unsigned short* __restrict__ Kgl,
                       const unsigned short* __restrict__ Vgh,
                       const unsigned short* __restrict__ Vgl,
                       float* __restrict__ ctx){
  __shared__ __align__(16) unsigned short EsH[64][72];
  __shared__ __align__(16) unsigned short EsL[64][72];
  int tid = threadIdx.x;
  int lane = tid & 63, w = tid >> 6;
  int lm = lane & 15, quad = lane >> 4;
  int b = blockIdx.x & 3, qb = blockIdx.x >> 2;   // qb 0..63
  int qrow0 = qb * 64;
  const unsigned short* KhB = Kgh + (size_t)b*NN*40;
  const unsigned short* KlB = Kgl + (size_t)b*NN*40;
  const unsigned short* VhB = Vgh + (size_t)b*64*192*64;
  const unsigned short* VlB = Vgl + (size_t)b*64*192*64;

  // S-phase roles: wave w -> qtile (w&3), ktiles {w>>2, (w>>2)+2}
  int s_qt = w & 3;
  int s_kt0 = w >> 2;
  s16x8 qh, ql;
  {
    size_t ro = (size_t)(qrow0 + s_qt*16 + lm)*40 + (size_t)quad*8;
    qh = *(const s16x8*)(KhB + ro);
    ql = *(const s16x8*)(KlB + ro);
  }
  // PV roles: qtiles {2*(w&1), 2*(w&1)+1}, ftiles {3*(w>>1)..+2}
  int p_qp = w & 1;
  int p_fg = w >> 1;
  f32x4 acc[2][3];
  #pragma unroll
  for(int q=0;q<2;q++)
    #pragma unroll
    for(int ft=0;ft<3;ft++)
      #pragma unroll
      for(int i=0;i<4;i++) acc[q][ft][i]=0.f;

  for(int it=0; it<NN/KT; ++it){
    int k0 = it*KT;
    // ---- S: scores via split-3 MFMA (no LDS deps)
    f32x4 sacc[2];
    #pragma unroll
    for(int t=0;t<2;t++){
      int kt = s_kt0 + 2*t;
      size_t ko = (size_t)(k0 + kt*16 + lm)*40 + (size_t)quad*8;
      s16x8 kh = *(const s16x8*)(KhB + ko);
      s16x8 kl = *(const s16x8*)(KlB + ko);
      f32x4 s = {0.f,0.f,0.f,0.f};
      s = __builtin_amdgcn_mfma_f32_16x16x32_bf16(ql, kh, s, 0,0,0);
      s = __builtin_amdgcn_mfma_f32_16x16x32_bf16(qh, kl, s, 0,0,0);
      s = __builtin_amdgcn_mfma_f32_16x16x32_bf16(qh, kh, s, 0,0,0);
      sacc[t]=s;
    }
    __syncthreads();   // prior-iter PV reads of Es are done
    #pragma unroll
    for(int t=0;t<2;t++){
      int kt = s_kt0 + 2*t;
      #pragma unroll
      for(int i=0;i<4;i++){
        float e = __expf(sacc[t][i]);
        unsigned short h = f2bf(e);
        float el = e - bf2f(h);
        int r = s_qt*16 + quad*4 + i;
        int c = kt*16 + lm;
        EsH[r][c] = h;
        EsL[r][c] = f2bf(el);
      }
    }
    __syncthreads();   // Es visible
    // ---- PV: split-3 MFMA, B-frags direct from global (L2)
    #pragma unroll
    for(int ks=0; ks<2; ks++){
      s16x8 eh[2], el[2];
      #pragma unroll
      for(int q=0;q<2;q++){
        int r = (2*p_qp + q)*16 + lm;
        eh[q] = *(const s16x8*)(&EsH[r][ks*32 + quad*8]);
        el[q] = *(const s16x8*)(&EsL[r][ks*32 + quad*8]);
      }
      #pragma unroll
      for(int ft=0; ft<3; ft++){
        int f = (3*p_fg + ft)*16 + lm;
        size_t vo = ((size_t)it*192 + f)*64 + (size_t)ks*32 + quad*8;
        s16x8 vh = *(const s16x8*)(VhB + vo);
        s16x8 vl = *(const s16x8*)(VlB + vo);
        #pragma unroll
        for(int q=0;q<2;q++){
          f32x4 a = acc[q][ft];
          a = __builtin_amdgcn_mfma_f32_16x16x32_bf16(el[q], vh, a, 0,0,0);
          a = __builtin_amdgcn_mfma_f32_16x16x32_bf16(eh[q], vl, a, 0,0,0);
          a = __builtin_amdgcn_mfma_f32_16x16x32_bf16(eh[q], vh, a, 0,0,0);
          acc[q][ft] = a;
        }
      }
    }
  }
  // epilogue: C layout col=lane&15, row=quad*4+reg
  #pragma unroll
  for(int q=0;q<2;q++){
    #pragma unroll
    for(int ft=0;ft<3;ft++){
      int col = (3*p_fg + ft)*16 + lm;
      #pragma unroll
      for(int i=0;i<4;i++){
        int row = qrow0 + (2*p_qp + q)*16 + quad*4 + i;
        ctx[((size_t)b*NN + row)*192 + col] = acc[q][ft][i];
      }
    }
  }
}

// ---------------------------------------------------------------- k_out
// block = 8 points x 32 lanes; lane kk<22 computes one output element
__launch_bounds__(256, 4)
__global__ void k_out(const float* __restrict__ feat, const float* __restrict__ ctx,
                      const float* __restrict__ w3jout, const float* __restrict__ scal,
                      float* __restrict__ out){
  __shared__ float Wo[10648];
  __shared__ float sc[64];
  __shared__ float g[8][96];
  __shared__ float fs[8][24];
  __shared__ float inv[8];
  int tid = threadIdx.x;
  for(int i=tid;i<10648;i+=256) Wo[i]=w3jout[i];
  if(tid<64) sc[tid]=scal[tid];
  int p = tid>>5, l5 = tid&31;
  int idx = blockIdx.x*8 + p;
  const float* cp = ctx + (size_t)idx*192;
  if(l5<22) fs[p][l5] = feat[(size_t)idx*22 + l5];
  if(l5==22) inv[p] = 1.0f / cp[176];
  // g[p][gi]: gi walks paths 0..7 with JD 9,13,9,13,...
  for(int gi=l5; gi<88; gi+=32){
    int pp=0, rem=gi;
    for(;;){ int jd = 9 + (pp&1)*4; if(rem<jd) break; rem-=jd; pp++; }
    int cb = (pp&1)*72;
    int jd = 9 + (pp&1)*4;
    float s=0.f;
    #pragma unroll
    for(int v=0;v<8;v++) s = fmaf(sc[pp*8+v], cp[cb + v*jd + rem], s);
    g[p][gi]=s;
  }
  __syncthreads();
  if(l5 < 22){
    int grp = (l5 < 9) ? 0 : 1;     // 0 -> d4 (paths 0..3, KD=9), 1 -> d6 (paths 4..7, KD=13)
    int kk  = grp ? (l5-9) : l5;
    int KD  = grp ? 13 : 9;
    float d = 0.f;
    const int IDs[4]={9,9,13,13}, JDs[4]={9,13,9,13}, FBs[4]={0,0,9,9};
    const int WoOff[8]={0,729,1782,2835,4356,5409,6930,8451};
    const int Goff[8]={0,9,22,31,44,53,66,75};
    #pragma unroll
    for(int s4=0;s4<4;s4++){
      const int ID=IDs[s4], JD=JDs[s4], FB=FBs[s4];
      int wb = (grp ? WoOff[s4+4] : WoOff[s4]) + kk;
      int gb = (grp ? Goff[s4+4] : Goff[s4]);
      for(int i=0;i<ID;i++){
        float fi = fs[p][FB+i];
        for(int j=0;j<JD;j++){
          d = fmaf(fi*g[p][gb+j], Wo[wb + (i*JD+j)*KD], d);
        }
      }
    }
    out[(size_t)idx*22 + l5] = d * inv[p];
  }
}

// ---------------------------------------------------------------- launch
extern "C" void kernel_launch(void* const* d_in, const int* in_sizes, int n_in,
                              void* d_out, int out_size, void* d_ws, size_t ws_size,
                              hipStream_t stream){
  (void)in_sizes; (void)n_in; (void)out_size; (void)ws_size;
  static float h_tab[13336];
  {
    const int vpth[6][3]={{4,0,4},{4,2,4},{6,2,4},{4,2,6},{6,0,6},{6,2,6}};
    const int voff[6]={0,81,486,1071,1656,1825};
    for(int p=0;p<6;p++){
      double scl = std::sqrt((2.0*vpth[p][2]+1.0)/(3.0*CCH));
      compute_w3j(vpth[p][0],vpth[p][1],vpth[p][2],scl,h_tab+voff[p]);
    }
    const int opth[8][3]={{4,4,4},{4,6,4},{6,4,4},{6,6,4},{4,4,6},{4,6,6},{6,4,6},{6,6,6}};
    const int ooff[8]={0,729,1782,2835,4356,5409,6930,8451};
    for(int p=0;p<8;p++){
      double scl = std::sqrt((2.0*opth[p][2]+1.0)/(4.0*CCH*CCH));
      compute_w3j(opth[p][0],opth[p][1],opth[p][2],scl,h_tab+2688+ooff[p]);
    }
  }
  float* wsf=(float*)d_ws;
  hipMemcpyAsync(wsf, h_tab, sizeof(h_tab), hipMemcpyHostToDevice, stream);

  const float* feat =(const float*)d_in[0];
  const float* sh   =(const float*)d_in[1];
  const float* log_s=(const float*)d_in[2];
  const float* pos_w=(const float*)d_in[3];
  const float* pos_b=(const float*)d_in[4];
  const float* wli  =(const float*)d_in[5];
  const float* wval =(const float*)d_in[6];
  const float* wout =(const float*)d_in[7];
  const float* wlo  =(const float*)d_in[8];
  float* outp=(float*)d_out;

  unsigned short* Kgh=(unsigned short*)((char*)d_ws + OFFB_KGH);
  unsigned short* Kgl=(unsigned short*)((char*)d_ws + OFFB_KGL);
  unsigned short* Vgh=(unsigned short*)((char*)d_ws + OFFB_VGH);
  unsigned short* Vgl=(unsigned short*)((char*)d_ws + OFFB_VGL);

  hipLaunchKernelGGL(k_weights, dim3(1), dim3(64), 0, stream,
                     wli, wval, wout, wlo, wsf+OFF_BW, wsf+OFF_SCAL);
  hipLaunchKernelGGL(k_prep, dim3(64), dim3(256), 0, stream,
                     feat, sh, log_s, pos_w, pos_b, wsf+OFF_W3JVAL, wsf+OFF_BW,
                     Kgh, Kgl, wsf+OFF_VP);
  hipLaunchKernelGGL(k_split, dim3(256), dim3(256), 0, stream,
                     wsf+OFF_VP, Vgh, Vgl);
  hipLaunchKernelGGL(k_attn, dim3(256), dim3(512), 0, stream,
                     Kgh, Kgl, Vgh, Vgl, wsf+OFF_CTX);
  hipLaunchKernelGGL(k_out, dim3(2048), dim3(256), 0, stream,
                     feat, wsf+OFF_CTX, wsf+OFF_W3JOUT, wsf+OFF_SCAL, outp);
}

// Round 3
// 470.165 us; speedup vs baseline: 4.8657x; 1.2915x over previous
//
#include <hip/hip_runtime.h>
#include <cmath>
#include <complex>
#include <vector>

#define NN 4096
#define BB 4
#define CCH 8
#define KT 64

// ---- workspace float offsets (fp32 region)
#define OFF_W3JVAL 0         // 2670 floats (pad to 2688)
#define OFF_W3JOUT 2688      // 10648 -> ends 13336 (pad 13440)
#define OFF_SCAL   13440     // 64 -> pad to 13568
#define OFF_CTX0   13568     // B*N*192 = 3145728 -> ends 3159296
#define OFF_CTX1   3159296   // -> ends 6305024 floats (25220096 B)
#define CTX_STRIDE 3145728
// ---- byte offsets (bf16 region), all 16B aligned
#define OFFB_KGH   25220096ULL   // u16[4*4096*40]  = 1310720 B
#define OFFB_KGL   26530816ULL
#define OFFB_VGH   27841536ULL   // u16[4*64*192*64] = 6291456 B
#define OFFB_VGL   34132992ULL   // end 40424448

typedef short s16x8 __attribute__((ext_vector_type(8)));
typedef float f32x4 __attribute__((ext_vector_type(4)));

static __device__ __forceinline__ unsigned short f2bf(float x){
  unsigned u = __float_as_uint(x);
  return (unsigned short)((u + 0x7FFFu + ((u >> 16) & 1u)) >> 16);
}
static __device__ __forceinline__ float bf2f(unsigned short h){
  return __uint_as_float(((unsigned)h) << 16);
}

// ---------------------------------------------------------------- host: Wigner 3j
namespace {
double dfact(int n){ double r=1.0; for(int i=2;i<=n;++i) r*=(double)i; return r; }

void compute_w3j(int l1,int l2,int l3,double scale,float* dst){
  int d1=2*l1+1,d2=2*l2+1,d3=2*l3+1;
  std::vector<double> Cc((size_t)d1*d2*d3,0.0);
  for(int i=0;i<d1;i++){int m1=i-l1;
   for(int j=0;j<d2;j++){int m2=j-l2;
    for(int k=0;k<d3;k++){int m3=k-l3;
      if(m1+m2!=m3) continue;
      double pref = std::sqrt((2.0*l3+1.0)*dfact(l3+l1-l2)*dfact(l3-l1+l2)*dfact(l1+l2-l3)/dfact(l1+l2+l3+1));
      pref *= std::sqrt(dfact(l3+m3)*dfact(l3-m3)*dfact(l1-m1)*dfact(l1+m1)*dfact(l2-m2)*dfact(l2+m2));
      double s=0.0;
      for(int kk=0;kk<=l1+l2-l3;kk++){
        int dd[6]={kk,l1+l2-l3-kk,l1-m1-kk,l2+m2-kk,l3-l2+m1+kk,l3-l1-m2+kk};
        int mn=dd[0]; for(int t=1;t<6;t++) if(dd[t]<mn) mn=dd[t];
        if(mn<0) continue;
        double prod=1.0; for(int t=0;t<6;t++) prod*=dfact(dd[t]);
        s += ((kk&1)?-1.0:1.0)/prod;
      }
      Cc[((size_t)i*d2+j)*d3+k]=pref*s;
    }}}
  auto qmat=[](int l){
    int d=2*l+1;
    std::vector<std::complex<double>> q((size_t)d*d,std::complex<double>(0,0));
    double rs2=1.0/std::sqrt(2.0);
    for(int m=-l;m<0;m++){
      q[(size_t)(l+m)*d+(l-m)]=std::complex<double>(rs2,0);
      q[(size_t)(l+m)*d+(l+m)]=std::complex<double>(0,-rs2);
    }
    q[(size_t)l*d+l]=std::complex<double>(1,0);
    for(int m=1;m<=l;m++){
      double sg=(m&1)?-1.0:1.0;
      q[(size_t)(l+m)*d+(l+m)]=std::complex<double>(sg*rs2,0);
      q[(size_t)(l+m)*d+(l-m)]=std::complex<double>(0,sg*rs2);
    }
    std::complex<double> f(1,0),mi(0,-1);
    for(int t=0;t<l;t++) f*=mi;
    for(auto&z:q) z*=f;
    return q;
  };
  auto Q1=qmat(l1),Q2=qmat(l2),Q3=qmat(l3);
  std::vector<std::complex<double>> T1((size_t)d1*d2*d3), T2((size_t)d1*d2*d3);
  for(int j=0;j<d1;j++) for(int k=0;k<d2;k++) for(int m=0;m<d3;m++){
    std::complex<double> s(0,0);
    for(int i=0;i<d1;i++) s += Q1[(size_t)i*d1+j]*Cc[((size_t)i*d2+k)*d3+m];
    T1[((size_t)j*d2+k)*d3+m]=s;
  }
  for(int j=0;j<d1;j++) for(int l=0;l<d2;l++) for(int m=0;m<d3;m++){
    std::complex<double> s(0,0);
    for(int k=0;k<d2;k++) s += Q2[(size_t)k*d2+l]*T1[((size_t)j*d2+k)*d3+m];
    T2[((size_t)j*d2+l)*d3+m]=s;
  }
  std::vector<double> Cr((size_t)d1*d2*d3);
  double nrm=0.0;
  for(int j=0;j<d1;j++) for(int l=0;l<d2;l++) for(int n=0;n<d3;n++){
    std::complex<double> s(0,0);
    for(int m=0;m<d3;m++) s += std::conj(Q3[(size_t)m*d3+n])*T2[((size_t)j*d2+l)*d3+m];
    double v=s.real();
    Cr[((size_t)j*d2+l)*d3+n]=v; nrm+=v*v;
  }
  nrm=std::sqrt(nrm);
  double c=scale/nrm;
  for(size_t t=0;t<Cr.size();t++) dst[t]=(float)(Cr[t]*c);
}
} // namespace

// ---------------------------------------------------------------- k_weights (scal only)
__global__ void k_weights(const float* __restrict__ wli, const float* __restrict__ wval,
                          const float* __restrict__ wout, const float* __restrict__ wlo,
                          float* __restrict__ scal){
  int t = threadIdx.x;
  const int out_l1[8]={0,0,1,1,0,0,1,1};
  const int out_l3[8]={0,0,0,0,1,1,1,1};
  int p=t>>3, v=t&7;
  float s=0.f;
  for(int u=0;u<8;u++){
    float a=wli[out_l1[p]*8+u];
    for(int w=0;w<8;w++) s = fmaf(wout[((p*8+u)*8+v)*8+w]*a, wlo[out_l3[p]*8+w], s);
  }
  scal[t]=s*0.35355339059327373f; // 1/sqrt(8)
}

// ---------------------------------------------------------------- k_prep
// grid 256 x 64 thr; block = one 64-point panel. Emits split-bf16 K rows and
// split-bf16 V panel DIRECTLY in transposed layout [panel][192][64] (thread==key).
__launch_bounds__(64,1)
__global__ void k_prep(const float* __restrict__ feat, const float* __restrict__ sh,
                       const float* __restrict__ log_s, const float* __restrict__ pos_w,
                       const float* __restrict__ pos_b, const float* __restrict__ w3jval,
                       const float* __restrict__ wli, const float* __restrict__ wval,
                       unsigned short* __restrict__ Kgh, unsigned short* __restrict__ Kgl,
                       unsigned short* __restrict__ Vgh, unsigned short* __restrict__ Vgl){
  __shared__ float Wv[2670];
  __shared__ float bws[48];
  int tid = threadIdx.x;
  for(int i=tid;i<2670;i+=64) Wv[i]=w3jval[i];
  if(tid<48){
    const int val_l1[6]={0,0,1,0,1,1};
    int p=tid>>3, w=tid&7;
    float s=0.f;
    for(int u=0;u<8;u++) s = fmaf(wli[val_l1[p]*8+u], wval[(p*8+u)*8+w], s);
    bws[tid]=s;
  }
  __syncthreads();
  int idx = blockIdx.x*64 + tid;   // 0..16383
  int n = idx & (NN-1);
  const float* fp = feat + (size_t)idx*22;
  const float* shp = sh + n*6;
  float f[22];
  #pragma unroll
  for(int c=0;c<22;c++) f[c]=fp[c];
  float n4=0.f, n6=0.f;
  #pragma unroll
  for(int c=0;c<9;c++) n4 += f[c]*f[c];
  #pragma unroll
  for(int c=9;c<22;c++) n6 += f[c]*f[c];
  n4 = fmaxf(sqrtf(n4), 1e-12f);
  n6 = fmaxf(sqrtf(n6), 1e-12f);
  float s4 = __expf(log_s[0]), s6 = __expf(log_s[1]);
  float a4 = sqrtf(s4)/n4, a6 = sqrtf(s6)/n6;
  {
    unsigned short* kh = Kgh + (size_t)idx*40;
    unsigned short* kl = Kgl + (size_t)idx*40;
    #pragma unroll
    for(int c=0;c<22;c++){
      float qv = f[c] * (c<9 ? a4 : a6);
      unsigned short h = f2bf(qv);
      kh[c]=h; kl[c]=f2bf(qv - bf2f(h));
    }
    #pragma unroll
    for(int c=22;c<40;c++){ kh[c]=0; kl[c]=0; }
  }
  float pb = pos_b[0];
  #pragma unroll
  for(int j=0;j<6;j++) pb = fmaf(shp[j], pos_w[j], pb);
  float epb = __expf(pb);
  float y0 = shp[0];
  float y2[5];
  #pragma unroll
  for(int j=0;j<5;j++) y2[j]=shp[1+j];

  float t0[9],t1[9],t2[9],t3[13],t4[13],t5[13];
  #pragma unroll
  for(int k=0;k<9;k++){t0[k]=0.f;t1[k]=0.f;t2[k]=0.f;}
  #pragma unroll
  for(int k=0;k<13;k++){t3[k]=0.f;t4[k]=0.f;t5[k]=0.f;}
  for(int i=0;i<9;i++){ float fi=f[i];
    #pragma unroll
    for(int k=0;k<9;k++) t0[k]=fmaf(fi,Wv[i*9+k],t0[k]); }
  #pragma unroll
  for(int k=0;k<9;k++) t0[k]*=y0;
  for(int i=0;i<9;i++){ float fi=f[i];
    #pragma unroll
    for(int j=0;j<5;j++){ float c_=fi*y2[j];
      #pragma unroll
      for(int k=0;k<9;k++) t1[k]=fmaf(c_,Wv[81+(i*5+j)*9+k],t1[k]); } }
  for(int i=0;i<13;i++){ float fi=f[9+i];
    #pragma unroll
    for(int j=0;j<5;j++){ float c_=fi*y2[j];
      #pragma unroll
      for(int k=0;k<9;k++) t2[k]=fmaf(c_,Wv[486+(i*5+j)*9+k],t2[k]); } }
  for(int i=0;i<9;i++){ float fi=f[i];
    #pragma unroll
    for(int j=0;j<5;j++){ float c_=fi*y2[j];
      #pragma unroll
      for(int k=0;k<13;k++) t3[k]=fmaf(c_,Wv[1071+(i*5+j)*13+k],t3[k]); } }
  for(int i=0;i<13;i++){ float fi=f[9+i];
    #pragma unroll
    for(int k=0;k<13;k++) t4[k]=fmaf(fi,Wv[1656+i*13+k],t4[k]); }
  #pragma unroll
  for(int k=0;k<13;k++) t4[k]*=y0;
  for(int i=0;i<13;i++){ float fi=f[9+i];
    #pragma unroll
    for(int j=0;j<5;j++){ float c_=fi*y2[j];
      #pragma unroll
      for(int k=0;k<13;k++) t5[k]=fmaf(c_,Wv[1825+(i*5+j)*13+k],t5[k]); } }

  // direct transposed split-bf16 V writes: thread == key within this panel
  size_t obase = (size_t)blockIdx.x * (192*64) + tid;
  for(int w=0;w<8;w++){
    float b0=bws[w], b1=bws[8+w], b2=bws[16+w];
    #pragma unroll
    for(int k=0;k<9;k++){
      float v = epb*(b0*t0[k]+b1*t1[k]+b2*t2[k]);
      unsigned short h = f2bf(v);
      size_t o = obase + (size_t)(w*9+k)*64;
      Vgh[o]=h; Vgl[o]=f2bf(v - bf2f(h));
    }
  }
  for(int w=0;w<8;w++){
    float b3=bws[24+w], b4=bws[32+w], b5=bws[40+w];
    #pragma unroll
    for(int k=0;k<13;k++){
      float v = epb*(b3*t3[k]+b4*t4[k]+b5*t5[k]);
      unsigned short h = f2bf(v);
      size_t o = obase + (size_t)(72+w*13+k)*64;
      Vgh[o]=h; Vgl[o]=f2bf(v - bf2f(h));
    }
  }
  {
    unsigned short h = f2bf(epb);
    size_t o = obase + (size_t)176*64;
    Vgh[o]=h; Vgl[o]=f2bf(epb - bf2f(h));
  }
  #pragma unroll
  for(int c=177;c<192;c++){
    size_t o = obase + (size_t)c*64;
    Vgh[o]=0; Vgl[o]=0;
  }
}

// ---------------------------------------------------------------- k_attn (MFMA split-bf16)
// Block: 512 thr (8 waves), 64 q-rows, KT=64 keys/iter, HALF the keys (32 panels).
// Grid 512 = 4b x 2kh x 64qb -> 2 blocks/CU. Each block writes its own ctx partial.
__launch_bounds__(512, 4)
__global__ void k_attn(const unsigned short* __restrict__ Kgh,
                       const unsigned short* __restrict__ Kgl,
                       const unsigned short* __restrict__ Vgh,
                       const unsigned short* __restrict__ Vgl,
                       float* __restrict__ ctx0){
  __shared__ __align__(16) unsigned short EsH[64][72];
  __shared__ __align__(16) unsigned short EsL[64][72];
  int tid = threadIdx.x;
  int lane = tid & 63, w = tid >> 6;
  int lm = lane & 15, quad = lane >> 4;
  int blk = blockIdx.x;
  int b = blk & 3, kh = (blk>>2) & 1, qb = blk >> 3;   // qb 0..63
  int qrow0 = qb * 64;
  const unsigned short* KhB = Kgh + (size_t)b*NN*40;
  const unsigned short* KlB = Kgl + (size_t)b*NN*40;
  const unsigned short* VhB = Vgh + (size_t)b*64*192*64;
  const unsigned short* VlB = Vgl + (size_t)b*64*192*64;
  float* ctx = ctx0 + (size_t)kh*CTX_STRIDE;

  // S-phase roles: wave w -> qtile (w&3), ktiles {w>>2, (w>>2)+2}
  int s_qt = w & 3;
  int s_kt0 = w >> 2;
  s16x8 qh, ql;
  {
    size_t ro = (size_t)(qrow0 + s_qt*16 + lm)*40 + (size_t)quad*8;
    qh = *(const s16x8*)(KhB + ro);
    ql = *(const s16x8*)(KlB + ro);
  }
  // PV roles: q-pair (w&1) -> qtiles {2*(w&1), +1}, ftiles {3*(w>>1)..+2}
  int p_qp = w & 1;
  int p_fg = w >> 1;
  f32x4 acc[2][3];
  #pragma unroll
  for(int q=0;q<2;q++)
    #pragma unroll
    for(int ft=0;ft<3;ft++)
      #pragma unroll
      for(int i=0;i<4;i++) acc[q][ft][i]=0.f;

  for(int it=kh*32; it<kh*32+32; ++it){
    int k0 = it*KT;
    // ---- S: scores via split-3 MFMA (no LDS deps)
    f32x4 sacc[2];
    #pragma unroll
    for(int t=0;t<2;t++){
      int kt = s_kt0 + 2*t;
      size_t ko = (size_t)(k0 + kt*16 + lm)*40 + (size_t)quad*8;
      s16x8 kh_ = *(const s16x8*)(KhB + ko);
      s16x8 kl_ = *(const s16x8*)(KlB + ko);
      f32x4 s = {0.f,0.f,0.f,0.f};
      s = __builtin_amdgcn_mfma_f32_16x16x32_bf16(ql, kh_, s, 0,0,0);
      s = __builtin_amdgcn_mfma_f32_16x16x32_bf16(qh, kl_, s, 0,0,0);
      s = __builtin_amdgcn_mfma_f32_16x16x32_bf16(qh, kh_, s, 0,0,0);
      sacc[t]=s;
    }
    __syncthreads();   // prior-iter PV reads of Es are done
    #pragma unroll
    for(int t=0;t<2;t++){
      int kt = s_kt0 + 2*t;
      #pragma unroll
      for(int i=0;i<4;i++){
        float e = __expf(sacc[t][i]);
        unsigned short h = f2bf(e);
        float el = e - bf2f(h);
        int r = s_qt*16 + quad*4 + i;
        int c = kt*16 + lm;
        EsH[r][c] = h;
        EsL[r][c] = f2bf(el);
      }
    }
    __syncthreads();   // Es visible
    // ---- PV: split-3 MFMA, B-frags direct from global (L1/L2)
    #pragma unroll
    for(int ks=0; ks<2; ks++){
      s16x8 eh[2], el[2];
      #pragma unroll
      for(int q=0;q<2;q++){
        int r = (2*p_qp + q)*16 + lm;
        eh[q] = *(const s16x8*)(&EsH[r][ks*32 + quad*8]);
        el[q] = *(const s16x8*)(&EsL[r][ks*32 + quad*8]);
      }
      #pragma unroll
      for(int ft=0; ft<3; ft++){
        int f = (3*p_fg + ft)*16 + lm;
        size_t vo = ((size_t)it*192 + f)*64 + (size_t)ks*32 + quad*8;
        s16x8 vh = *(const s16x8*)(VhB + vo);
        s16x8 vl = *(const s16x8*)(VlB + vo);
        #pragma unroll
        for(int q=0;q<2;q++){
          f32x4 a = acc[q][ft];
          a = __builtin_amdgcn_mfma_f32_16x16x32_bf16(el[q], vh, a, 0,0,0);
          a = __builtin_amdgcn_mfma_f32_16x16x32_bf16(eh[q], vl, a, 0,0,0);
          a = __builtin_amdgcn_mfma_f32_16x16x32_bf16(eh[q], vh, a, 0,0,0);
          acc[q][ft] = a;
        }
      }
    }
  }
  // epilogue: C layout col=lane&15, row=quad*4+reg
  #pragma unroll
  for(int q=0;q<2;q++){
    #pragma unroll
    for(int ft=0;ft<3;ft++){
      int col = (3*p_fg + ft)*16 + lm;
      #pragma unroll
      for(int i=0;i<4;i++){
        int row = qrow0 + (2*p_qp + q)*16 + quad*4 + i;
        ctx[((size_t)b*NN + row)*192 + col] = acc[q][ft][i];
      }
    }
  }
}

// ---------------------------------------------------------------- k_out
// block = 8 points x 32 lanes; sums the two ctx partials
__launch_bounds__(256, 4)
__global__ void k_out(const float* __restrict__ feat, const float* __restrict__ ctxA,
                      const float* __restrict__ w3jout, const float* __restrict__ scal,
                      float* __restrict__ out){
  __shared__ float Wo[10648];
  __shared__ float sc[64];
  __shared__ float g[8][96];
  __shared__ float fs[8][24];
  __shared__ float inv[8];
  int tid = threadIdx.x;
  for(int i=tid;i<10648;i+=256) Wo[i]=w3jout[i];
  if(tid<64) sc[tid]=scal[tid];
  int p = tid>>5, l5 = tid&31;
  int idx = blockIdx.x*8 + p;
  const float* cp0 = ctxA + (size_t)idx*192;
  const float* cp1 = cp0 + CTX_STRIDE;
  if(l5<22) fs[p][l5] = feat[(size_t)idx*22 + l5];
  if(l5==22) inv[p] = 1.0f / (cp0[176]+cp1[176]);
  // g[p][gi]: gi walks paths 0..7 with JD 9,13,9,13,...
  for(int gi=l5; gi<88; gi+=32){
    int pp=0, rem=gi;
    for(;;){ int jd = 9 + (pp&1)*4; if(rem<jd) break; rem-=jd; pp++; }
    int cb = (pp&1)*72;
    int jd = 9 + (pp&1)*4;
    float s=0.f;
    #pragma unroll
    for(int v=0;v<8;v++) s = fmaf(sc[pp*8+v], cp0[cb+v*jd+rem]+cp1[cb+v*jd+rem], s);
    g[p][gi]=s;
  }
  __syncthreads();
  if(l5 < 22){
    int grp = (l5 < 9) ? 0 : 1;     // 0 -> d4 (paths 0..3, KD=9), 1 -> d6 (paths 4..7, KD=13)
    int kk  = grp ? (l5-9) : l5;
    int KD  = grp ? 13 : 9;
    float d = 0.f;
    const int IDs[4]={9,9,13,13}, JDs[4]={9,13,9,13}, FBs[4]={0,0,9,9};
    const int WoOff[8]={0,729,1782,2835,4356,5409,6930,8451};
    const int Goff[8]={0,9,22,31,44,53,66,75};
    #pragma unroll
    for(int s4=0;s4<4;s4++){
      const int ID=IDs[s4], JD=JDs[s4], FB=FBs[s4];
      int wb = (grp ? WoOff[s4+4] : WoOff[s4]) + kk;
      int gb = (grp ? Goff[s4+4] : Goff[s4]);
      for(int i=0;i<ID;i++){
        float fi = fs[p][FB+i];
        for(int j=0;j<JD;j++){
          d = fmaf(fi*g[p][gb+j], Wo[wb + (i*JD+j)*KD], d);
        }
      }
    }
    out[(size_t)idx*22 + l5] = d * inv[p];
  }
}

// ---------------------------------------------------------------- launch
extern "C" void kernel_launch(void* const* d_in, const int* in_sizes, int n_in,
                              void* d_out, int out_size, void* d_ws, size_t ws_size,
                              hipStream_t stream){
  (void)in_sizes; (void)n_in; (void)out_size; (void)ws_size;
  static float h_tab[13336];
  {
    const int vpth[6][3]={{4,0,4},{4,2,4},{6,2,4},{4,2,6},{6,0,6},{6,2,6}};
    const int voff[6]={0,81,486,1071,1656,1825};
    for(int p=0;p<6;p++){
      double scl = std::sqrt((2.0*vpth[p][2]+1.0)/(3.0*CCH));
      compute_w3j(vpth[p][0],vpth[p][1],vpth[p][2],scl,h_tab+voff[p]);
    }
    const int opth[8][3]={{4,4,4},{4,6,4},{6,4,4},{6,6,4},{4,4,6},{4,6,6},{6,4,6},{6,6,6}};
    const int ooff[8]={0,729,1782,2835,4356,5409,6930,8451};
    for(int p=0;p<8;p++){
      double scl = std::sqrt((2.0*opth[p][2]+1.0)/(4.0*CCH*CCH));
      compute_w3j(opth[p][0],opth[p][1],opth[p][2],scl,h_tab+2688+ooff[p]);
    }
  }
  float* wsf=(float*)d_ws;
  hipMemcpyAsync(wsf, h_tab, sizeof(h_tab), hipMemcpyHostToDevice, stream);

  const float* feat =(const float*)d_in[0];
  const float* sh   =(const float*)d_in[1];
  const float* log_s=(const float*)d_in[2];
  const float* pos_w=(const float*)d_in[3];
  const float* pos_b=(const float*)d_in[4];
  const float* wli  =(const float*)d_in[5];
  const float* wval =(const float*)d_in[6];
  const float* wout =(const float*)d_in[7];
  const float* wlo  =(const float*)d_in[8];
  float* outp=(float*)d_out;

  unsigned short* Kgh=(unsigned short*)((char*)d_ws + OFFB_KGH);
  unsigned short* Kgl=(unsigned short*)((char*)d_ws + OFFB_KGL);
  unsigned short* Vgh=(unsigned short*)((char*)d_ws + OFFB_VGH);
  unsigned short* Vgl=(unsigned short*)((char*)d_ws + OFFB_VGL);

  hipLaunchKernelGGL(k_weights, dim3(1), dim3(64), 0, stream,
                     wli, wval, wout, wlo, wsf+OFF_SCAL);
  hipLaunchKernelGGL(k_prep, dim3(256), dim3(64), 0, stream,
                     feat, sh, log_s, pos_w, pos_b, wsf+OFF_W3JVAL, wli, wval,
                     Kgh, Kgl, Vgh, Vgl);
  hipLaunchKernelGGL(k_attn, dim3(512), dim3(512), 0, stream,
                     Kgh, Kgl, Vgh, Vgl, wsf+OFF_CTX0);
  hipLaunchKernelGGL(k_out, dim3(2048), dim3(256), 0, stream,
                     feat, wsf+OFF_CTX0, wsf+OFF_W3JOUT, wsf+OFF_SCAL, outp);
}

// Round 4
// 469.334 us; speedup vs baseline: 4.8744x; 1.0018x over previous
//
#include <hip/hip_runtime.h>
#include <cmath>
#include <complex>
#include <vector>

#define NN 4096
#define BB 4
#define CCH 8
#define KT 64

// ---- workspace float offsets (fp32 region)
#define OFF_W3JVAL 0         // 2670 floats (pad to 2688)
#define OFF_W3JOUT 2688      // 10648 -> ends 13336 (pad 13440)
#define OFF_SCAL   13440     // 64 -> pad to 13568
#define OFF_CTX0   13568     // B*N*192 = 3145728 -> ends 3159296
#define OFF_CTX1   3159296   // -> ends 6305024 floats (25220096 B)
#define CTX_STRIDE 3145728
// ---- byte offsets (bf16 region), all 16B aligned
#define OFFB_KGH   25220096ULL   // u16[4*4096*40]  = 1310720 B
#define OFFB_KGL   26530816ULL
#define OFFB_VGH   27841536ULL   // u16[4*64*192*64] = 6291456 B
#define OFFB_VGL   34132992ULL   // end 40424448

typedef short s16x8 __attribute__((ext_vector_type(8)));
typedef float f32x4 __attribute__((ext_vector_type(4)));
typedef unsigned int u32x4 __attribute__((ext_vector_type(4)));

static __device__ __forceinline__ unsigned short f2bf(float x){
  unsigned u = __float_as_uint(x);
  return (unsigned short)((u + 0x7FFFu + ((u >> 16) & 1u)) >> 16);
}
static __device__ __forceinline__ float bf2f(unsigned short h){
  return __uint_as_float(((unsigned)h) << 16);
}
// barrier that orders LDS only — does NOT drain global loads (vmcnt untouched).
// Cross-wave communication in the K-loop is exclusively through LDS, so
// lgkmcnt(0)+s_barrier is sufficient; avoids HIP __syncthreads' vmcnt(0) drain.
static __device__ __forceinline__ void barrier_lds(){
  __asm__ volatile("s_waitcnt lgkmcnt(0)\n\ts_barrier" ::: "memory");
}

// ---------------------------------------------------------------- host: Wigner 3j
namespace {
double dfact(int n){ double r=1.0; for(int i=2;i<=n;++i) r*=(double)i; return r; }

void compute_w3j(int l1,int l2,int l3,double scale,float* dst){
  int d1=2*l1+1,d2=2*l2+1,d3=2*l3+1;
  std::vector<double> Cc((size_t)d1*d2*d3,0.0);
  for(int i=0;i<d1;i++){int m1=i-l1;
   for(int j=0;j<d2;j++){int m2=j-l2;
    for(int k=0;k<d3;k++){int m3=k-l3;
      if(m1+m2!=m3) continue;
      double pref = std::sqrt((2.0*l3+1.0)*dfact(l3+l1-l2)*dfact(l3-l1+l2)*dfact(l1+l2-l3)/dfact(l1+l2+l3+1));
      pref *= std::sqrt(dfact(l3+m3)*dfact(l3-m3)*dfact(l1-m1)*dfact(l1+m1)*dfact(l2-m2)*dfact(l2+m2));
      double s=0.0;
      for(int kk=0;kk<=l1+l2-l3;kk++){
        int dd[6]={kk,l1+l2-l3-kk,l1-m1-kk,l2+m2-kk,l3-l2+m1+kk,l3-l1-m2+kk};
        int mn=dd[0]; for(int t=1;t<6;t++) if(dd[t]<mn) mn=dd[t];
        if(mn<0) continue;
        double prod=1.0; for(int t=0;t<6;t++) prod*=dfact(dd[t]);
        s += ((kk&1)?-1.0:1.0)/prod;
      }
      Cc[((size_t)i*d2+j)*d3+k]=pref*s;
    }}}
  auto qmat=[](int l){
    int d=2*l+1;
    std::vector<std::complex<double>> q((size_t)d*d,std::complex<double>(0,0));
    double rs2=1.0/std::sqrt(2.0);
    for(int m=-l;m<0;m++){
      q[(size_t)(l+m)*d+(l-m)]=std::complex<double>(rs2,0);
      q[(size_t)(l+m)*d+(l+m)]=std::complex<double>(0,-rs2);
    }
    q[(size_t)l*d+l]=std::complex<double>(1,0);
    for(int m=1;m<=l;m++){
      double sg=(m&1)?-1.0:1.0;
      q[(size_t)(l+m)*d+(l+m)]=std::complex<double>(sg*rs2,0);
      q[(size_t)(l+m)*d+(l-m)]=std::complex<double>(0,sg*rs2);
    }
    std::complex<double> f(1,0),mi(0,-1);
    for(int t=0;t<l;t++) f*=mi;
    for(auto&z:q) z*=f;
    return q;
  };
  auto Q1=qmat(l1),Q2=qmat(l2),Q3=qmat(l3);
  std::vector<std::complex<double>> T1((size_t)d1*d2*d3), T2((size_t)d1*d2*d3);
  for(int j=0;j<d1;j++) for(int k=0;k<d2;k++) for(int m=0;m<d3;m++){
    std::complex<double> s(0,0);
    for(int i=0;i<d1;i++) s += Q1[(size_t)i*d1+j]*Cc[((size_t)i*d2+k)*d3+m];
    T1[((size_t)j*d2+k)*d3+m]=s;
  }
  for(int j=0;j<d1;j++) for(int l=0;l<d2;l++) for(int m=0;m<d3;m++){
    std::complex<double> s(0,0);
    for(int k=0;k<d2;k++) s += Q2[(size_t)k*d2+l]*T1[((size_t)j*d2+k)*d3+m];
    T2[((size_t)j*d2+l)*d3+m]=s;
  }
  std::vector<double> Cr((size_t)d1*d2*d3);
  double nrm=0.0;
  for(int j=0;j<d1;j++) for(int l=0;l<d2;l++) for(int n=0;n<d3;n++){
    std::complex<double> s(0,0);
    for(int m=0;m<d3;m++) s += std::conj(Q3[(size_t)m*d3+n])*T2[((size_t)j*d2+l)*d3+m];
    double v=s.real();
    Cr[((size_t)j*d2+l)*d3+n]=v; nrm+=v*v;
  }
  nrm=std::sqrt(nrm);
  double c=scale/nrm;
  for(size_t t=0;t<Cr.size();t++) dst[t]=(float)(Cr[t]*c);
}
} // namespace

// ---------------------------------------------------------------- k_weights (scal only)
__global__ void k_weights(const float* __restrict__ wli, const float* __restrict__ wval,
                          const float* __restrict__ wout, const float* __restrict__ wlo,
                          float* __restrict__ scal){
  int t = threadIdx.x;
  const int out_l1[8]={0,0,1,1,0,0,1,1};
  const int out_l3[8]={0,0,0,0,1,1,1,1};
  int p=t>>3, v=t&7;
  float s=0.f;
  for(int u=0;u<8;u++){
    float a=wli[out_l1[p]*8+u];
    for(int w=0;w<8;w++) s = fmaf(wout[((p*8+u)*8+v)*8+w]*a, wlo[out_l3[p]*8+w], s);
  }
  scal[t]=s*0.35355339059327373f; // 1/sqrt(8)
}

// ---------------------------------------------------------------- k_prep
// grid 256 x 64 thr; block = one 64-point panel. Emits split-bf16 K rows and
// split-bf16 V panel DIRECTLY in transposed layout [panel][192][64] (thread==key).
__launch_bounds__(64,1)
__global__ void k_prep(const float* __restrict__ feat, const float* __restrict__ sh,
                       const float* __restrict__ log_s, const float* __restrict__ pos_w,
                       const float* __restrict__ pos_b, const float* __restrict__ w3jval,
                       const float* __restrict__ wli, const float* __restrict__ wval,
                       unsigned short* __restrict__ Kgh, unsigned short* __restrict__ Kgl,
                       unsigned short* __restrict__ Vgh, unsigned short* __restrict__ Vgl){
  __shared__ float Wv[2670];
  __shared__ float bws[48];
  int tid = threadIdx.x;
  for(int i=tid;i<2670;i+=64) Wv[i]=w3jval[i];
  if(tid<48){
    const int val_l1[6]={0,0,1,0,1,1};
    int p=tid>>3, w=tid&7;
    float s=0.f;
    for(int u=0;u<8;u++) s = fmaf(wli[val_l1[p]*8+u], wval[(p*8+u)*8+w], s);
    bws[tid]=s;
  }
  __syncthreads();
  int idx = blockIdx.x*64 + tid;   // 0..16383
  int n = idx & (NN-1);
  const float* fp = feat + (size_t)idx*22;
  const float* shp = sh + n*6;
  float f[22];
  #pragma unroll
  for(int c=0;c<22;c++) f[c]=fp[c];
  float n4=0.f, n6=0.f;
  #pragma unroll
  for(int c=0;c<9;c++) n4 += f[c]*f[c];
  #pragma unroll
  for(int c=9;c<22;c++) n6 += f[c]*f[c];
  n4 = fmaxf(sqrtf(n4), 1e-12f);
  n6 = fmaxf(sqrtf(n6), 1e-12f);
  float s4 = __expf(log_s[0]), s6 = __expf(log_s[1]);
  float a4 = sqrtf(s4)/n4, a6 = sqrtf(s6)/n6;
  {
    unsigned short* kh = Kgh + (size_t)idx*40;
    unsigned short* kl = Kgl + (size_t)idx*40;
    #pragma unroll
    for(int c=0;c<22;c++){
      float qv = f[c] * (c<9 ? a4 : a6);
      unsigned short h = f2bf(qv);
      kh[c]=h; kl[c]=f2bf(qv - bf2f(h));
    }
    #pragma unroll
    for(int c=22;c<40;c++){ kh[c]=0; kl[c]=0; }
  }
  float pb = pos_b[0];
  #pragma unroll
  for(int j=0;j<6;j++) pb = fmaf(shp[j], pos_w[j], pb);
  float epb = __expf(pb);
  float y0 = shp[0];
  float y2[5];
  #pragma unroll
  for(int j=0;j<5;j++) y2[j]=shp[1+j];

  float t0[9],t1[9],t2[9],t3[13],t4[13],t5[13];
  #pragma unroll
  for(int k=0;k<9;k++){t0[k]=0.f;t1[k]=0.f;t2[k]=0.f;}
  #pragma unroll
  for(int k=0;k<13;k++){t3[k]=0.f;t4[k]=0.f;t5[k]=0.f;}
  for(int i=0;i<9;i++){ float fi=f[i];
    #pragma unroll
    for(int k=0;k<9;k++) t0[k]=fmaf(fi,Wv[i*9+k],t0[k]); }
  #pragma unroll
  for(int k=0;k<9;k++) t0[k]*=y0;
  for(int i=0;i<9;i++){ float fi=f[i];
    #pragma unroll
    for(int j=0;j<5;j++){ float c_=fi*y2[j];
      #pragma unroll
      for(int k=0;k<9;k++) t1[k]=fmaf(c_,Wv[81+(i*5+j)*9+k],t1[k]); } }
  for(int i=0;i<13;i++){ float fi=f[9+i];
    #pragma unroll
    for(int j=0;j<5;j++){ float c_=fi*y2[j];
      #pragma unroll
      for(int k=0;k<9;k++) t2[k]=fmaf(c_,Wv[486+(i*5+j)*9+k],t2[k]); } }
  for(int i=0;i<9;i++){ float fi=f[i];
    #pragma unroll
    for(int j=0;j<5;j++){ float c_=fi*y2[j];
      #pragma unroll
      for(int k=0;k<13;k++) t3[k]=fmaf(c_,Wv[1071+(i*5+j)*13+k],t3[k]); } }
  for(int i=0;i<13;i++){ float fi=f[9+i];
    #pragma unroll
    for(int k=0;k<13;k++) t4[k]=fmaf(fi,Wv[1656+i*13+k],t4[k]); }
  #pragma unroll
  for(int k=0;k<13;k++) t4[k]*=y0;
  for(int i=0;i<13;i++){ float fi=f[9+i];
    #pragma unroll
    for(int j=0;j<5;j++){ float c_=fi*y2[j];
      #pragma unroll
      for(int k=0;k<13;k++) t5[k]=fmaf(c_,Wv[1825+(i*5+j)*13+k],t5[k]); } }

  // direct transposed split-bf16 V writes: thread == key within this panel
  size_t obase = (size_t)blockIdx.x * (192*64) + tid;
  for(int w=0;w<8;w++){
    float b0=bws[w], b1=bws[8+w], b2=bws[16+w];
    #pragma unroll
    for(int k=0;k<9;k++){
      float v = epb*(b0*t0[k]+b1*t1[k]+b2*t2[k]);
      unsigned short h = f2bf(v);
      size_t o = obase + (size_t)(w*9+k)*64;
      Vgh[o]=h; Vgl[o]=f2bf(v - bf2f(h));
    }
  }
  for(int w=0;w<8;w++){
    float b3=bws[24+w], b4=bws[32+w], b5=bws[40+w];
    #pragma unroll
    for(int k=0;k<13;k++){
      float v = epb*(b3*t3[k]+b4*t4[k]+b5*t5[k]);
      unsigned short h = f2bf(v);
      size_t o = obase + (size_t)(72+w*13+k)*64;
      Vgh[o]=h; Vgl[o]=f2bf(v - bf2f(h));
    }
  }
  {
    unsigned short h = f2bf(epb);
    size_t o = obase + (size_t)176*64;
    Vgh[o]=h; Vgl[o]=f2bf(epb - bf2f(h));
  }
  #pragma unroll
  for(int c=177;c<192;c++){
    size_t o = obase + (size_t)c*64;
    Vgh[o]=0; Vgl[o]=0;
  }
}

// ---------------------------------------------------------------- k_attn (MFMA split-bf16)
// Block: 512 thr (8 waves), 64 q-rows, KT=64 keys/iter, half the keys (32 panels).
// Grid 512 = 4b x 2kh x 64qb -> 2 blocks/CU. LDS-only barriers; packed Es.
#define ESTRIDE 68   // u32 stride: 272 B, 16B-aligned rows, <=2-way bank aliasing
__launch_bounds__(512, 4)
__global__ void k_attn(const unsigned short* __restrict__ Kgh,
                       const unsigned short* __restrict__ Kgl,
                       const unsigned short* __restrict__ Vgh,
                       const unsigned short* __restrict__ Vgl,
                       float* __restrict__ ctx0){
  __shared__ __align__(16) unsigned int EsP[64*ESTRIDE];   // (el<<16)|eh packed
  int tid = threadIdx.x;
  int lane = tid & 63, w = tid >> 6;
  int lm = lane & 15, quad = lane >> 4;
  int blk = blockIdx.x;
  int b = blk & 3, kh = (blk>>2) & 1, qb = blk >> 3;   // qb 0..63
  int qrow0 = qb * 64;
  const unsigned short* KhB = Kgh + (size_t)b*NN*40;
  const unsigned short* KlB = Kgl + (size_t)b*NN*40;
  const unsigned short* VhB = Vgh + (size_t)b*64*192*64;
  const unsigned short* VlB = Vgl + (size_t)b*64*192*64;
  float* ctx = ctx0 + (size_t)kh*CTX_STRIDE;

  // S-phase roles: wave w -> qtile (w&3), ktiles {w>>2, (w>>2)+2}
  int s_qt = w & 3;
  int s_kt0 = w >> 2;
  s16x8 qh, ql;
  {
    size_t ro = (size_t)(qrow0 + s_qt*16 + lm)*40 + (size_t)quad*8;
    qh = *(const s16x8*)(KhB + ro);
    ql = *(const s16x8*)(KlB + ro);
  }
  // PV roles: q-pair (w&1) -> qtiles {2*(w&1), +1}, ftiles {3*(w>>1)..+2}
  int p_qp = w & 1;
  int p_fg = w >> 1;
  f32x4 acc[2][3];
  #pragma unroll
  for(int q=0;q<2;q++)
    #pragma unroll
    for(int ft=0;ft<3;ft++)
      #pragma unroll
      for(int i=0;i<4;i++) acc[q][ft][i]=0.f;

  for(int it=kh*32; it<kh*32+32; ++it){
    int k0 = it*KT;
    // ---- S: scores via split-3 MFMA (global loads, no LDS deps)
    f32x4 sacc[2];
    #pragma unroll
    for(int t=0;t<2;t++){
      int kt = s_kt0 + 2*t;
      size_t ko = (size_t)(k0 + kt*16 + lm)*40 + (size_t)quad*8;
      s16x8 kh_ = *(const s16x8*)(KhB + ko);
      s16x8 kl_ = *(const s16x8*)(KlB + ko);
      f32x4 s = {0.f,0.f,0.f,0.f};
      s = __builtin_amdgcn_mfma_f32_16x16x32_bf16(ql, kh_, s, 0,0,0);
      s = __builtin_amdgcn_mfma_f32_16x16x32_bf16(qh, kl_, s, 0,0,0);
      s = __builtin_amdgcn_mfma_f32_16x16x32_bf16(qh, kh_, s, 0,0,0);
      sacc[t]=s;
    }
    barrier_lds();   // prior-iter PV reads of EsP are done (lgkm only)
    #pragma unroll
    for(int t=0;t<2;t++){
      int kt = s_kt0 + 2*t;
      #pragma unroll
      for(int i=0;i<4;i++){
        float e = __expf(sacc[t][i]);
        unsigned short h = f2bf(e);
        unsigned short l = f2bf(e - bf2f(h));
        int r = s_qt*16 + quad*4 + i;
        int c = kt*16 + lm;
        EsP[r*ESTRIDE + c] = ((unsigned)l << 16) | (unsigned)h;
      }
    }
    barrier_lds();   // EsP visible (lgkm only — global loads stay in flight)
    // ---- PV: split-3 MFMA, B-frags direct from global (L1/L2)
    #pragma unroll
    for(int ks=0; ks<2; ks++){
      s16x8 eh[2], el[2];
      #pragma unroll
      for(int q=0;q<2;q++){
        int r = (2*p_qp + q)*16 + lm;
        const u32x4* pp = (const u32x4*)(&EsP[r*ESTRIDE + ks*32 + quad*8]);
        u32x4 pA = pp[0], pB = pp[1];
        unsigned hv[4], lv[4];
        hv[0]=__builtin_amdgcn_perm(pA[1],pA[0],0x05040100u);
        lv[0]=__builtin_amdgcn_perm(pA[1],pA[0],0x07060302u);
        hv[1]=__builtin_amdgcn_perm(pA[3],pA[2],0x05040100u);
        lv[1]=__builtin_amdgcn_perm(pA[3],pA[2],0x07060302u);
        hv[2]=__builtin_amdgcn_perm(pB[1],pB[0],0x05040100u);
        lv[2]=__builtin_amdgcn_perm(pB[1],pB[0],0x07060302u);
        hv[3]=__builtin_amdgcn_perm(pB[3],pB[2],0x05040100u);
        lv[3]=__builtin_amdgcn_perm(pB[3],pB[2],0x07060302u);
        u32x4 hw = {hv[0],hv[1],hv[2],hv[3]};
        u32x4 lw = {lv[0],lv[1],lv[2],lv[3]};
        eh[q] = __builtin_bit_cast(s16x8, hw);
        el[q] = __builtin_bit_cast(s16x8, lw);
      }
      #pragma unroll
      for(int ft=0; ft<3; ft++){
        int f = (3*p_fg + ft)*16 + lm;
        size_t vo = ((size_t)it*192 + f)*64 + (size_t)ks*32 + quad*8;
        s16x8 vh = *(const s16x8*)(VhB + vo);
        s16x8 vl = *(const s16x8*)(VlB + vo);
        #pragma unroll
        for(int q=0;q<2;q++){
          f32x4 a = acc[q][ft];
          a = __builtin_amdgcn_mfma_f32_16x16x32_bf16(el[q], vh, a, 0,0,0);
          a = __builtin_amdgcn_mfma_f32_16x16x32_bf16(eh[q], vl, a, 0,0,0);
          a = __builtin_amdgcn_mfma_f32_16x16x32_bf16(eh[q], vh, a, 0,0,0);
          acc[q][ft] = a;
        }
      }
    }
  }
  // epilogue: C layout col=lane&15, row=quad*4+reg
  #pragma unroll
  for(int q=0;q<2;q++){
    #pragma unroll
    for(int ft=0;ft<3;ft++){
      int col = (3*p_fg + ft)*16 + lm;
      #pragma unroll
      for(int i=0;i<4;i++){
        int row = qrow0 + (2*p_qp + q)*16 + quad*4 + i;
        ctx[((size_t)b*NN + row)*192 + col] = acc[q][ft][i];
      }
    }
  }
}

// ---------------------------------------------------------------- k_out
// block = 8 points x 32 lanes; sums the two ctx partials
__launch_bounds__(256, 4)
__global__ void k_out(const float* __restrict__ feat, const float* __restrict__ ctxA,
                      const float* __restrict__ w3jout, const float* __restrict__ scal,
                      float* __restrict__ out){
  __shared__ float Wo[10648];
  __shared__ float sc[64];
  __shared__ float g[8][96];
  __shared__ float fs[8][24];
  __shared__ float inv[8];
  int tid = threadIdx.x;
  for(int i=tid;i<10648;i+=256) Wo[i]=w3jout[i];
  if(tid<64) sc[tid]=scal[tid];
  int p = tid>>5, l5 = tid&31;
  int idx = blockIdx.x*8 + p;
  const float* cp0 = ctxA + (size_t)idx*192;
  const float* cp1 = cp0 + CTX_STRIDE;
  if(l5<22) fs[p][l5] = feat[(size_t)idx*22 + l5];
  if(l5==22) inv[p] = 1.0f / (cp0[176]+cp1[176]);
  // g[p][gi]: gi walks paths 0..7 with JD 9,13,9,13,...
  for(int gi=l5; gi<88; gi+=32){
    int pp=0, rem=gi;
    for(;;){ int jd = 9 + (pp&1)*4; if(rem<jd) break; rem-=jd; pp++; }
    int cb = (pp&1)*72;
    int jd = 9 + (pp&1)*4;
    float s=0.f;
    #pragma unroll
    for(int v=0;v<8;v++) s = fmaf(sc[pp*8+v], cp0[cb+v*jd+rem]+cp1[cb+v*jd+rem], s);
    g[p][gi]=s;
  }
  __syncthreads();
  if(l5 < 22){
    int grp = (l5 < 9) ? 0 : 1;     // 0 -> d4 (paths 0..3, KD=9), 1 -> d6 (paths 4..7, KD=13)
    int kk  = grp ? (l5-9) : l5;
    int KD  = grp ? 13 : 9;
    float d = 0.f;
    const int IDs[4]={9,9,13,13}, JDs[4]={9,13,9,13}, FBs[4]={0,0,9,9};
    const int WoOff[8]={0,729,1782,2835,4356,5409,6930,8451};
    const int Goff[8]={0,9,22,31,44,53,66,75};
    #pragma unroll
    for(int s4=0;s4<4;s4++){
      const int ID=IDs[s4], JD=JDs[s4], FB=FBs[s4];
      int wb = (grp ? WoOff[s4+4] : WoOff[s4]) + kk;
      int gb = (grp ? Goff[s4+4] : Goff[s4]);
      for(int i=0;i<ID;i++){
        float fi = fs[p][FB+i];
        for(int j=0;j<JD;j++){
          d = fmaf(fi*g[p][gb+j], Wo[wb + (i*JD+j)*KD], d);
        }
      }
    }
    out[(size_t)idx*22 + l5] = d * inv[p];
  }
}

// ---------------------------------------------------------------- launch
extern "C" void kernel_launch(void* const* d_in, const int* in_sizes, int n_in,
                              void* d_out, int out_size, void* d_ws, size_t ws_size,
                              hipStream_t stream){
  (void)in_sizes; (void)n_in; (void)out_size; (void)ws_size;
  static float h_tab[13336];
  {
    const int vpth[6][3]={{4,0,4},{4,2,4},{6,2,4},{4,2,6},{6,0,6},{6,2,6}};
    const int voff[6]={0,81,486,1071,1656,1825};
    for(int p=0;p<6;p++){
      double scl = std::sqrt((2.0*vpth[p][2]+1.0)/(3.0*CCH));
      compute_w3j(vpth[p][0],vpth[p][1],vpth[p][2],scl,h_tab+voff[p]);
    }
    const int opth[8][3]={{4,4,4},{4,6,4},{6,4,4},{6,6,4},{4,4,6},{4,6,6},{6,4,6},{6,6,6}};
    const int ooff[8]={0,729,1782,2835,4356,5409,6930,8451};
    for(int p=0;p<8;p++){
      double scl = std::sqrt((2.0*opth[p][2]+1.0)/(4.0*CCH*CCH));
      compute_w3j(opth[p][0],opth[p][1],opth[p][2],scl,h_tab+2688+ooff[p]);
    }
  }
  float* wsf=(float*)d_ws;
  hipMemcpyAsync(wsf, h_tab, sizeof(h_tab), hipMemcpyHostToDevice, stream);

  const float* feat =(const float*)d_in[0];
  const float* sh   =(const float*)d_in[1];
  const float* log_s=(const float*)d_in[2];
  const float* pos_w=(const float*)d_in[3];
  const float* pos_b=(const float*)d_in[4];
  const float* wli  =(const float*)d_in[5];
  const float* wval =(const float*)d_in[6];
  const float* wout =(const float*)d_in[7];
  const float* wlo  =(const float*)d_in[8];
  float* outp=(float*)d_out;

  unsigned short* Kgh=(unsigned short*)((char*)d_ws + OFFB_KGH);
  unsigned short* Kgl=(unsigned short*)((char*)d_ws + OFFB_KGL);
  unsigned short* Vgh=(unsigned short*)((char*)d_ws + OFFB_VGH);
  unsigned short* Vgl=(unsigned short*)((char*)d_ws + OFFB_VGL);

  hipLaunchKernelGGL(k_weights, dim3(1), dim3(64), 0, stream,
                     wli, wval, wout, wlo, wsf+OFF_SCAL);
  hipLaunchKernelGGL(k_prep, dim3(256), dim3(64), 0, stream,
                     feat, sh, log_s, pos_w, pos_b, wsf+OFF_W3JVAL, wli, wval,
                     Kgh, Kgl, Vgh, Vgl);
  hipLaunchKernelGGL(k_attn, dim3(512), dim3(512), 0, stream,
                     Kgh, Kgl, Vgh, Vgl, wsf+OFF_CTX0);
  hipLaunchKernelGGL(k_out, dim3(2048), dim3(256), 0, stream,
                     feat, wsf+OFF_CTX0, wsf+OFF_W3JOUT, wsf+OFF_SCAL, outp);
}

// Round 5
// 279.016 us; speedup vs baseline: 8.1992x; 1.6821x over previous
//
#include <hip/hip_runtime.h>
#include <cmath>
#include <complex>
#include <vector>

#define NN 4096
#define BB 4
#define CCH 8

// ---- workspace float offsets
#define OFF_W3JVAL 0         // 2670 (pad 2688)
#define OFF_W3JOUT 2688      // 10648 -> 13336 (pad 13440)
#define OFF_A      13440     // 24 (pad to 13568)
#define OFF_CTX0   13568     // 4 partials x 4*4096*96 = 6291456 -> ends 6305024 floats
#define CTXS       1572864
// ---- byte offsets (packed u32 region)
#define OFFB_KG    25220096ULL   // u32[4*4096*32]   = 2097152 B
#define OFFB_VG    27317248ULL   // u32[4*64*96*64]  = 6291456 B -> ends 33608704

typedef short s16x8 __attribute__((ext_vector_type(8)));
typedef float f32x4 __attribute__((ext_vector_type(4)));
typedef unsigned int u32x4 __attribute__((ext_vector_type(4)));

static __device__ __forceinline__ unsigned short f2bf(float x){
  unsigned u = __float_as_uint(x);
  return (unsigned short)((u + 0x7FFFu + ((u >> 16) & 1u)) >> 16);
}
static __device__ __forceinline__ float bf2f(unsigned short h){
  return __uint_as_float(((unsigned)h) << 16);
}
static __device__ __forceinline__ unsigned pk2(float v){
  unsigned short h = f2bf(v);
  unsigned short l = f2bf(v - bf2f(h));
  return ((unsigned)l << 16) | (unsigned)h;
}
// unpack 8 packed u32 -> (high s16x8, low s16x8)
static __device__ __forceinline__ void unpk(u32x4 a, u32x4 b, s16x8& h, s16x8& l){
  u32x4 hw = { __builtin_amdgcn_perm(a[1],a[0],0x05040100u),
               __builtin_amdgcn_perm(a[3],a[2],0x05040100u),
               __builtin_amdgcn_perm(b[1],b[0],0x05040100u),
               __builtin_amdgcn_perm(b[3],b[2],0x05040100u)};
  u32x4 lw = { __builtin_amdgcn_perm(a[1],a[0],0x07060302u),
               __builtin_amdgcn_perm(a[3],a[2],0x07060302u),
               __builtin_amdgcn_perm(b[1],b[0],0x07060302u),
               __builtin_amdgcn_perm(b[3],b[2],0x07060302u)};
  h = __builtin_bit_cast(s16x8, hw);
  l = __builtin_bit_cast(s16x8, lw);
}

// ---------------------------------------------------------------- host: Wigner 3j
namespace {
double dfact(int n){ double r=1.0; for(int i=2;i<=n;++i) r*=(double)i; return r; }

void compute_w3j(int l1,int l2,int l3,double scale,float* dst){
  int d1=2*l1+1,d2=2*l2+1,d3=2*l3+1;
  std::vector<double> Cc((size_t)d1*d2*d3,0.0);
  for(int i=0;i<d1;i++){int m1=i-l1;
   for(int j=0;j<d2;j++){int m2=j-l2;
    for(int k=0;k<d3;k++){int m3=k-l3;
      if(m1+m2!=m3) continue;
      double pref = std::sqrt((2.0*l3+1.0)*dfact(l3+l1-l2)*dfact(l3-l1+l2)*dfact(l1+l2-l3)/dfact(l1+l2+l3+1));
      pref *= std::sqrt(dfact(l3+m3)*dfact(l3-m3)*dfact(l1-m1)*dfact(l1+m1)*dfact(l2-m2)*dfact(l2+m2));
      double s=0.0;
      for(int kk=0;kk<=l1+l2-l3;kk++){
        int dd[6]={kk,l1+l2-l3-kk,l1-m1-kk,l2+m2-kk,l3-l2+m1+kk,l3-l1-m2+kk};
        int mn=dd[0]; for(int t=1;t<6;t++) if(dd[t]<mn) mn=dd[t];
        if(mn<0) continue;
        double prod=1.0; for(int t=0;t<6;t++) prod*=dfact(dd[t]);
        s += ((kk&1)?-1.0:1.0)/prod;
      }
      Cc[((size_t)i*d2+j)*d3+k]=pref*s;
    }}}
  auto qmat=[](int l){
    int d=2*l+1;
    std::vector<std::complex<double>> q((size_t)d*d,std::complex<double>(0,0));
    double rs2=1.0/std::sqrt(2.0);
    for(int m=-l;m<0;m++){
      q[(size_t)(l+m)*d+(l-m)]=std::complex<double>(rs2,0);
      q[(size_t)(l+m)*d+(l+m)]=std::complex<double>(0,-rs2);
    }
    q[(size_t)l*d+l]=std::complex<double>(1,0);
    for(int m=1;m<=l;m++){
      double sg=(m&1)?-1.0:1.0;
      q[(size_t)(l+m)*d+(l+m)]=std::complex<double>(sg*rs2,0);
      q[(size_t)(l+m)*d+(l-m)]=std::complex<double>(0,sg*rs2);
    }
    std::complex<double> f(1,0),mi(0,-1);
    for(int t=0;t<l;t++) f*=mi;
    for(auto&z:q) z*=f;
    return q;
  };
  auto Q1=qmat(l1),Q2=qmat(l2),Q3=qmat(l3);
  std::vector<std::complex<double>> T1((size_t)d1*d2*d3), T2((size_t)d1*d2*d3);
  for(int j=0;j<d1;j++) for(int k=0;k<d2;k++) for(int m=0;m<d3;m++){
    std::complex<double> s(0,0);
    for(int i=0;i<d1;i++) s += Q1[(size_t)i*d1+j]*Cc[((size_t)i*d2+k)*d3+m];
    T1[((size_t)j*d2+k)*d3+m]=s;
  }
  for(int j=0;j<d1;j++) for(int l=0;l<d2;l++) for(int m=0;m<d3;m++){
    std::complex<double> s(0,0);
    for(int k=0;k<d2;k++) s += Q2[(size_t)k*d2+l]*T1[((size_t)j*d2+k)*d3+m];
    T2[((size_t)j*d2+l)*d3+m]=s;
  }
  std::vector<double> Cr((size_t)d1*d2*d3);
  double nrm=0.0;
  for(int j=0;j<d1;j++) for(int l=0;l<d2;l++) for(int n=0;n<d3;n++){
    std::complex<double> s(0,0);
    for(int m=0;m<d3;m++) s += std::conj(Q3[(size_t)m*d3+n])*T2[((size_t)j*d2+l)*d3+m];
    double v=s.real();
    Cr[((size_t)j*d2+l)*d3+n]=v; nrm+=v*v;
  }
  nrm=std::sqrt(nrm);
  double c=scale/nrm;
  for(size_t t=0;t<Cr.size();t++) dst[t]=(float)(Cr[t]*c);
}
} // namespace

// ---------------------------------------------------------------- k_weights
// A[p][i] = sum_w scal[p][w] * bw[val_path(p,i)][w]  (24 floats)
__global__ void k_weights(const float* __restrict__ wli, const float* __restrict__ wval,
                          const float* __restrict__ wout, const float* __restrict__ wlo,
                          float* __restrict__ Aout){
  __shared__ float bws[48];
  __shared__ float scs[64];
  int t = threadIdx.x;
  if(t<48){
    const int val_l1[6]={0,0,1,0,1,1};
    int p=t>>3, w=t&7;
    float s=0.f;
    for(int u=0;u<8;u++) s = fmaf(wli[val_l1[p]*8+u], wval[(p*8+u)*8+w], s);
    bws[t]=s;
  }
  {
    const int out_l1[8]={0,0,1,1,0,0,1,1};
    const int out_l3[8]={0,0,0,0,1,1,1,1};
    int p=t>>3, v=t&7;
    float s=0.f;
    for(int u=0;u<8;u++){
      float a=wli[out_l1[p]*8+u];
      for(int w=0;w<8;w++) s = fmaf(wout[((p*8+u)*8+v)*8+w]*a, wlo[out_l3[p]*8+w], s);
    }
    scs[t]=s*0.35355339059327373f; // 1/sqrt(8)
  }
  __syncthreads();
  if(t<24){
    int p=t/3, i3=t-3*p;
    // even p (l2=4) -> val paths 0..2 ; odd p (l2=6) -> val paths 3..5
    int vp = (p&1)*3 + i3;
    float s=0.f;
    for(int w=0;w<8;w++) s = fmaf(scs[p*8+w], bws[vp*8+w], s);
    Aout[t]=s;
  }
}

// ---------------------------------------------------------------- k_prep
// grid 128 x 128 thr. Per point: packed split-bf16 K row (32 u32, cols>=22 zero)
// + packed pre-contracted 96-feature V in transposed layout [panel][96][64]:
//   features 0..87 = g-features (path-major 9,13,9,13,...), 88 = e^pb, 89..95 = 0.
__launch_bounds__(128,1)
__global__ void k_prep(const float* __restrict__ feat, const float* __restrict__ sh,
                       const float* __restrict__ log_s, const float* __restrict__ pos_w,
                       const float* __restrict__ pos_b, const float* __restrict__ w3jval,
                       const float* __restrict__ Aw,
                       unsigned int* __restrict__ Kg, unsigned int* __restrict__ Vg){
  __shared__ float Wv[2670];
  __shared__ float As[24];
  int tid = threadIdx.x;
  for(int i=tid;i<2670;i+=128) Wv[i]=w3jval[i];
  if(tid<24) As[tid]=Aw[tid];
  __syncthreads();
  int idx = blockIdx.x*128 + tid;   // 0..16383
  int n = idx & (NN-1);
  const float* fp = feat + (size_t)idx*22;
  const float* shp = sh + n*6;
  float f[22];
  #pragma unroll
  for(int c=0;c<22;c++) f[c]=fp[c];
  float n4=0.f, n6=0.f;
  #pragma unroll
  for(int c=0;c<9;c++) n4 += f[c]*f[c];
  #pragma unroll
  for(int c=9;c<22;c++) n6 += f[c]*f[c];
  n4 = fmaxf(sqrtf(n4), 1e-12f);
  n6 = fmaxf(sqrtf(n6), 1e-12f);
  float s4 = __expf(log_s[0]), s6 = __expf(log_s[1]);
  float a4 = sqrtf(s4)/n4, a6 = sqrtf(s6)/n6;
  {
    unsigned int* kp = Kg + (size_t)idx*32;
    #pragma unroll
    for(int c=0;c<22;c++) kp[c] = pk2(f[c] * (c<9 ? a4 : a6));
    #pragma unroll
    for(int c=22;c<32;c++) kp[c]=0u;
  }
  float pb = pos_b[0];
  #pragma unroll
  for(int j=0;j<6;j++) pb = fmaf(shp[j], pos_w[j], pb);
  float epb = __expf(pb);
  float y0 = shp[0];
  float y2[5];
  #pragma unroll
  for(int j=0;j<5;j++) y2[j]=shp[1+j];

  unsigned int* vbase = Vg + (size_t)(idx>>6)*(96*64) + (idx&63);
  // ---- pass 1: l3=4 val paths -> even out-paths
  {
    float t0[9],t1[9],t2[9];
    #pragma unroll
    for(int k=0;k<9;k++){t0[k]=0.f;t1[k]=0.f;t2[k]=0.f;}
    for(int i=0;i<9;i++){ float fi=f[i];
      #pragma unroll
      for(int k=0;k<9;k++) t0[k]=fmaf(fi,Wv[i*9+k],t0[k]); }
    #pragma unroll
    for(int k=0;k<9;k++) t0[k]*=y0;
    for(int i=0;i<9;i++){ float fi=f[i];
      #pragma unroll
      for(int j=0;j<5;j++){ float c_=fi*y2[j];
        #pragma unroll
        for(int k=0;k<9;k++) t1[k]=fmaf(c_,Wv[81+(i*5+j)*9+k],t1[k]); } }
    for(int i=0;i<13;i++){ float fi=f[9+i];
      #pragma unroll
      for(int j=0;j<5;j++){ float c_=fi*y2[j];
        #pragma unroll
        for(int k=0;k<9;k++) t2[k]=fmaf(c_,Wv[486+(i*5+j)*9+k],t2[k]); } }
    const int Ge[4]={0,22,44,66};
    #pragma unroll
    for(int pi=0;pi<4;pi++){
      int p=2*pi;
      float A0=As[p*3], A1=As[p*3+1], A2=As[p*3+2];
      #pragma unroll
      for(int j=0;j<9;j++){
        float v = epb*(A0*t0[j]+A1*t1[j]+A2*t2[j]);
        vbase[(size_t)(Ge[pi]+j)*64] = pk2(v);
      }
    }
  }
  // ---- pass 2: l3=6 val paths -> odd out-paths
  {
    float t3[13],t4[13],t5[13];
    #pragma unroll
    for(int k=0;k<13;k++){t3[k]=0.f;t4[k]=0.f;t5[k]=0.f;}
    for(int i=0;i<9;i++){ float fi=f[i];
      #pragma unroll
      for(int j=0;j<5;j++){ float c_=fi*y2[j];
        #pragma unroll
        for(int k=0;k<13;k++) t3[k]=fmaf(c_,Wv[1071+(i*5+j)*13+k],t3[k]); } }
    for(int i=0;i<13;i++){ float fi=f[9+i];
      #pragma unroll
      for(int k=0;k<13;k++) t4[k]=fmaf(fi,Wv[1656+i*13+k],t4[k]); }
    #pragma unroll
    for(int k=0;k<13;k++) t4[k]*=y0;
    for(int i=0;i<13;i++){ float fi=f[9+i];
      #pragma unroll
      for(int j=0;j<5;j++){ float c_=fi*y2[j];
        #pragma unroll
        for(int k=0;k<13;k++) t5[k]=fmaf(c_,Wv[1825+(i*5+j)*13+k],t5[k]); } }
    const int Go[4]={9,31,53,75};
    #pragma unroll
    for(int pi=0;pi<4;pi++){
      int p=2*pi+1;
      float A0=As[p*3], A1=As[p*3+1], A2=As[p*3+2];
      #pragma unroll
      for(int j=0;j<13;j++){
        float v = epb*(A0*t3[j]+A1*t4[j]+A2*t5[j]);
        vbase[(size_t)(Go[pi]+j)*64] = pk2(v);
      }
    }
  }
  vbase[(size_t)88*64] = pk2(epb);
  #pragma unroll
  for(int c=89;c<96;c++) vbase[(size_t)c*64]=0u;
}

// ---------------------------------------------------------------- k_attn
// grid 256 = 4b x 4kh x 16qb; block 512 thr (8 waves), BM=256 q rows,
// KT=64 keys/iter, 16 iters. ctx partial per kh. Split-3 bf16 MFMA.
#define ESTRIDE 68
__launch_bounds__(512, 2)
__global__ void k_attn(const unsigned int* __restrict__ Kg,
                       const unsigned int* __restrict__ Vg,
                       float* __restrict__ ctx0){
  __shared__ __align__(16) unsigned int EsP[256*ESTRIDE];   // 69632 B
  int tid = threadIdx.x;
  int lane = tid & 63, w = tid >> 6;
  int lm = lane & 15, quad = lane >> 4;
  int blk = blockIdx.x;
  int b = blk & 3, kh = (blk>>2)&3, qb = blk >> 4;   // qb 0..15
  int qrow0 = qb * 256;
  const unsigned int* KgB = Kg + (size_t)b*NN*32;
  const unsigned int* VgB = Vg + (size_t)b*64*96*64;
  float* ctx = ctx0 + (size_t)kh*CTXS + (size_t)b*NN*96;

  // Q fragments for this wave's 2 S q-tiles {2w, 2w+1}
  s16x8 qh[2], ql[2];
  #pragma unroll
  for(int qq=0;qq<2;qq++){
    const unsigned int* qp = KgB + (size_t)(qrow0 + (2*w+qq)*16 + lm)*32 + quad*8;
    unpk(*(const u32x4*)qp, *(const u32x4*)(qp+4), qh[qq], ql[qq]);
  }
  int qbase = (w & 3)*4;     // PV q-tiles
  int fbase = (w >> 2)*3;    // PV f-tiles
  f32x4 acc[4][3];
  #pragma unroll
  for(int qt=0;qt<4;qt++)
    #pragma unroll
    for(int ft=0;ft<3;ft++)
      #pragma unroll
      for(int i=0;i<4;i++) acc[qt][ft][i]=0.f;

  // prefetch K for first iter
  u32x4 kbufA[4], kbufB[4];
  {
    int key0 = (kh*16)*64;
    #pragma unroll
    for(int kt=0;kt<4;kt++){
      const unsigned int* kp = KgB + (size_t)(key0 + kt*16 + lm)*32 + quad*8;
      kbufA[kt]=*(const u32x4*)kp; kbufB[kt]=*(const u32x4*)(kp+4);
    }
  }

  for(int it=0; it<16; ++it){
    int panel = kh*16 + it;
    // ---- V loads for this iter (issue early; drained by barrier below)
    u32x4 vbufA[3][2], vbufB[3][2];
    #pragma unroll
    for(int ft=0;ft<3;ft++)
      #pragma unroll
      for(int ks=0;ks<2;ks++){
        const unsigned int* vp = VgB + ((size_t)panel*96 + (fbase+ft)*16 + lm)*64 + ks*32 + quad*8;
        vbufA[ft][ks]=*(const u32x4*)vp; vbufB[ft][ks]=*(const u32x4*)(vp+4);
      }
    // ---- S: unpack K, 3-MFMA per (qq,kt)
    s16x8 khh[4], kll[4];
    #pragma unroll
    for(int kt=0;kt<4;kt++) unpk(kbufA[kt], kbufB[kt], khh[kt], kll[kt]);
    f32x4 sacc[2][4];
    #pragma unroll
    for(int qq=0;qq<2;qq++)
      #pragma unroll
      for(int kt=0;kt<4;kt++){
        f32x4 s = {0.f,0.f,0.f,0.f};
        s = __builtin_amdgcn_mfma_f32_16x16x32_bf16(ql[qq], khh[kt], s, 0,0,0);
        s = __builtin_amdgcn_mfma_f32_16x16x32_bf16(qh[qq], kll[kt], s, 0,0,0);
        s = __builtin_amdgcn_mfma_f32_16x16x32_bf16(qh[qq], khh[kt], s, 0,0,0);
        sacc[qq][kt]=s;
      }
    // ---- K prefetch for next iter
    if(it<15){
      int key0n = (panel+1)*64;
      #pragma unroll
      for(int kt=0;kt<4;kt++){
        const unsigned int* kp = KgB + (size_t)(key0n + kt*16 + lm)*32 + quad*8;
        kbufA[kt]=*(const u32x4*)kp; kbufB[kt]=*(const u32x4*)(kp+4);
      }
    }
    __syncthreads();   // prior-iter PV reads of EsP done (V/K loads already landed)
    #pragma unroll
    for(int qq=0;qq<2;qq++)
      #pragma unroll
      for(int kt=0;kt<4;kt++){
        #pragma unroll
        for(int i=0;i<4;i++){
          float e = __expf(sacc[qq][kt][i]);
          EsP[((2*w+qq)*16 + quad*4 + i)*ESTRIDE + kt*16 + lm] = pk2(e);
        }
      }
    __syncthreads();   // EsP visible
    // ---- PV
    #pragma unroll
    for(int ks=0; ks<2; ks++){
      s16x8 eh[4], el[4];
      #pragma unroll
      for(int qt=0;qt<4;qt++){
        const u32x4* pp = (const u32x4*)&EsP[((qbase+qt)*16 + lm)*ESTRIDE + ks*32 + quad*8];
        unpk(pp[0], pp[1], eh[qt], el[qt]);
      }
      #pragma unroll
      for(int ft=0; ft<3; ft++){
        s16x8 vh, vl;
        unpk(vbufA[ft][ks], vbufB[ft][ks], vh, vl);
        #pragma unroll
        for(int qt=0;qt<4;qt++){
          f32x4 a = acc[qt][ft];
          a = __builtin_amdgcn_mfma_f32_16x16x32_bf16(el[qt], vh, a, 0,0,0);
          a = __builtin_amdgcn_mfma_f32_16x16x32_bf16(eh[qt], vl, a, 0,0,0);
          a = __builtin_amdgcn_mfma_f32_16x16x32_bf16(eh[qt], vh, a, 0,0,0);
          acc[qt][ft] = a;
        }
      }
    }
  }
  // epilogue: C layout col=lane&15, row=quad*4+reg
  #pragma unroll
  for(int qt=0;qt<4;qt++){
    #pragma unroll
    for(int ft=0;ft<3;ft++){
      int col = (fbase+ft)*16 + lm;
      #pragma unroll
      for(int i=0;i<4;i++){
        int row = qrow0 + (qbase+qt)*16 + quad*4 + i;
        ctx[(size_t)row*96 + col] = acc[qt][ft][i];
      }
    }
  }
}

// ---------------------------------------------------------------- k_out
// block = 8 points x 32 lanes; g = sum of 4 ctx partials (already sc-contracted)
__launch_bounds__(256, 4)
__global__ void k_out(const float* __restrict__ feat, const float* __restrict__ ctxA,
                      const float* __restrict__ w3jout, float* __restrict__ out){
  __shared__ float Wo[10648];
  __shared__ float g[8][96];
  __shared__ float fs[8][24];
  __shared__ float inv[8];
  int tid = threadIdx.x;
  for(int i=tid;i<10648;i+=256) Wo[i]=w3jout[i];
  int p = tid>>5, l5 = tid&31;
  int idx = blockIdx.x*8 + p;
  const float* cp0 = ctxA + (size_t)idx*96;
  const float* cp1 = cp0 + CTXS;
  const float* cp2 = cp0 + 2*CTXS;
  const float* cp3 = cp0 + 3*CTXS;
  if(l5<22) fs[p][l5] = feat[(size_t)idx*22 + l5];
  if(l5==22) inv[p] = 1.0f / (cp0[88]+cp1[88]+cp2[88]+cp3[88]);
  for(int gi=l5; gi<88; gi+=32)
    g[p][gi] = cp0[gi]+cp1[gi]+cp2[gi]+cp3[gi];
  __syncthreads();
  if(l5 < 22){
    int grp = (l5 < 9) ? 0 : 1;
    int kk  = grp ? (l5-9) : l5;
    int KD  = grp ? 13 : 9;
    float d = 0.f;
    const int IDs[4]={9,9,13,13}, JDs[4]={9,13,9,13}, FBs[4]={0,0,9,9};
    const int WoOff[8]={0,729,1782,2835,4356,5409,6930,8451};
    const int Goff[8]={0,9,22,31,44,53,66,75};
    #pragma unroll
    for(int s4=0;s4<4;s4++){
      const int ID=IDs[s4], JD=JDs[s4], FB=FBs[s4];
      int wb = (grp ? WoOff[s4+4] : WoOff[s4]) + kk;
      int gb = (grp ? Goff[s4+4] : Goff[s4]);
      for(int i=0;i<ID;i++){
        float fi = fs[p][FB+i];
        for(int j=0;j<JD;j++){
          d = fmaf(fi*g[p][gb+j], Wo[wb + (i*JD+j)*KD], d);
        }
      }
    }
    out[(size_t)idx*22 + l5] = d * inv[p];
  }
}

// ---------------------------------------------------------------- launch
extern "C" void kernel_launch(void* const* d_in, const int* in_sizes, int n_in,
                              void* d_out, int out_size, void* d_ws, size_t ws_size,
                              hipStream_t stream){
  (void)in_sizes; (void)n_in; (void)out_size; (void)ws_size;
  static float h_tab[13336];
  {
    const int vpth[6][3]={{4,0,4},{4,2,4},{6,2,4},{4,2,6},{6,0,6},{6,2,6}};
    const int voff[6]={0,81,486,1071,1656,1825};
    for(int p=0;p<6;p++){
      double scl = std::sqrt((2.0*vpth[p][2]+1.0)/(3.0*CCH));
      compute_w3j(vpth[p][0],vpth[p][1],vpth[p][2],scl,h_tab+voff[p]);
    }
    const int opth[8][3]={{4,4,4},{4,6,4},{6,4,4},{6,6,4},{4,4,6},{4,6,6},{6,4,6},{6,6,6}};
    const int ooff[8]={0,729,1782,2835,4356,5409,6930,8451};
    for(int p=0;p<8;p++){
      double scl = std::sqrt((2.0*opth[p][2]+1.0)/(4.0*CCH*CCH));
      compute_w3j(opth[p][0],opth[p][1],opth[p][2],scl,h_tab+2688+ooff[p]);
    }
  }
  float* wsf=(float*)d_ws;
  hipMemcpyAsync(wsf, h_tab, sizeof(h_tab), hipMemcpyHostToDevice, stream);

  const float* feat =(const float*)d_in[0];
  const float* sh   =(const float*)d_in[1];
  const float* log_s=(const float*)d_in[2];
  const float* pos_w=(const float*)d_in[3];
  const float* pos_b=(const float*)d_in[4];
  const float* wli  =(const float*)d_in[5];
  const float* wval =(const float*)d_in[6];
  const float* wout =(const float*)d_in[7];
  const float* wlo  =(const float*)d_in[8];
  float* outp=(float*)d_out;

  unsigned int* Kg=(unsigned int*)((char*)d_ws + OFFB_KG);
  unsigned int* Vg=(unsigned int*)((char*)d_ws + OFFB_VG);

  hipLaunchKernelGGL(k_weights, dim3(1), dim3(64), 0, stream,
                     wli, wval, wout, wlo, wsf+OFF_A);
  hipLaunchKernelGGL(k_prep, dim3(128), dim3(128), 0, stream,
                     feat, sh, log_s, pos_w, pos_b, wsf+OFF_W3JVAL, wsf+OFF_A,
                     Kg, Vg);
  hipLaunchKernelGGL(k_attn, dim3(256), dim3(512), 0, stream,
                     Kg, Vg, wsf+OFF_CTX0);
  hipLaunchKernelGGL(k_out, dim3(2048), dim3(256), 0, stream,
                     feat, wsf+OFF_CTX0, wsf+OFF_W3JOUT, outp);
}